// Round 10
// baseline (284.068 us; speedup 1.0000x reference)
//
#include <hip/hip_runtime.h>

// MultiHeadAttention: B=4, S=2048, D=1024, H=16, dk=dv=64.
// Inputs fp32, output fp32; compute bf16 MFMA.
// R9: attention computes S^T = K·Q^T so P^T exits MFMA in a layout reachable
// from the PV B-operand by a pure lane permutation -- no P LDS round-trip.
// R10: attn VALU diet: builtin exp2, ones-MFMA denominator, v_perm pack.
// R12: ds_bpermute -> permlane32/16_swap: conflicts 8.4M->0, attn 112->83us.
// R13: gemm_bt double-buffered, 1 barrier/K-step.
// R16: pack_all LDS-transpose (-19us).  R17: out tile shape NEUTRAL.
// R18: QKV XCD-chunked swizzle (-3.5us); attn setprio (-1.7us).
// R19: QKV rewritten as 256^2/BK=64/512-thread fine-phased kernel (T3+T4+T5):
// 4 phases/tile, ONE half-tile (2 loads/thread) staged per phase in order
// [B0,B1,A0,A1], counted vmcnt(2) only at phase 0 (never vmcnt(0) in loop).
// Safety: phase-0 stage is a B-half while the only cross-tile straggler phase
// reads A rows 96-127 (disjoint arrays); every wave's vmcnt(2)+barrier at
// phase 0 proves all stripes of tile t landed.  attn/pack/out untouched.

typedef __attribute__((ext_vector_type(8))) short bf16x8;   // 8 bf16 = 4 VGPRs
typedef __attribute__((ext_vector_type(4))) float f32x4;
typedef __attribute__((ext_vector_type(4))) unsigned short ushortx4;
typedef __attribute__((ext_vector_type(2))) unsigned int uint2v;

__device__ __forceinline__ unsigned short f2bf(float x) {   // RNE
    unsigned int u = __float_as_uint(x);
    u += 0x7FFFu + ((u >> 16) & 1u);
    return (unsigned short)(u >> 16);
}
// pack two floats as truncated bf16 pair: [hi.bf16 : lo.bf16] -- v_perm_b32
__device__ __forceinline__ unsigned int pack_bf2(float hi, float lo) {
    return __builtin_amdgcn_perm(__float_as_uint(hi), __float_as_uint(lo), 0x07060302u);
}

// async 16B global -> LDS (lds dest wave-uniform; HW adds lane*16)
__device__ __forceinline__ void gload_lds16(const unsigned short* g, unsigned short* lds) {
    __builtin_amdgcn_global_load_lds(
        (const __attribute__((address_space(1))) unsigned int*)g,
        (__attribute__((address_space(3))) unsigned int*)lds,
        16, 0, 0);
}

// ---------------------------------------------------------------------------
// One merged pack kernel. Sections by blockIdx.x:
//  [0,4096):      XB  = bf16(x)                       (coalesced)
//  [4096,4480):   WQKVT[n][d]  via LDS-transposed tiles (Wq scaled)
//  [4480,4608):   WOT[n][k] = Wo[k][n] via LDS-transposed tiles
__global__ __launch_bounds__(256) void pack_all(
    const float* __restrict__ x,
    const float* __restrict__ Wq,
    const float* __restrict__ Wk,
    const float* __restrict__ Wv,
    const float* __restrict__ Wo,
    unsigned short* __restrict__ XB,
    unsigned short* __restrict__ WQKVT,
    unsigned short* __restrict__ WOT)
{
    const int bid = blockIdx.x;
    const int tid = threadIdx.x;
    if (bid < 4096) {
        bf16x8 v;
        size_t base = ((size_t)bid * 256 + tid) * 8;
        float4 f0 = *(const float4*)&x[base];
        float4 f1 = *(const float4*)&x[base + 4];
        v[0] = f2bf(f0.x); v[1] = f2bf(f0.y); v[2] = f2bf(f0.z); v[3] = f2bf(f0.w);
        v[4] = f2bf(f1.x); v[5] = f2bf(f1.y); v[6] = f2bf(f1.z); v[7] = f2bf(f1.w);
        *(bf16x8*)&XB[base] = v;
        return;
    }

    __shared__ float lds[64 * 129];
    const float* src;
    size_t outbase;
    float scale = 1.0f;
    int instride;
    unsigned short* outp;
    if (bid < 4480) {
        const int widx = bid - 4096;
        const int part = widx >> 7;           // 0..2 (q,k,v)
        const int rem  = widx & 127;
        const int h    = rem >> 3;            // 0..15
        const int chunk = rem & 7;            // d-chunk of 128
        const float* W = (part == 0) ? Wq : ((part == 1) ? Wk : Wv);
        src = W + h * 65536 + chunk * 8192;   // [128 d][64 kk], row stride 64
        instride = 64;
        outbase = ((size_t)(part * 1024 + h * 64)) * 1024 + chunk * 128;
        if (part == 0) scale = 0.125f * 1.44269504088896f;
        outp = WQKVT;
    } else {
        const int oidx = bid - 4480;
        const int kc = oidx >> 4;             // k-chunk of 128 (0..7)
        const int nc = oidx & 15;             // n-chunk of 64  (0..15)
        src = Wo + (size_t)kc * 128 * 1024 + nc * 64;   // [128 k][64 n], stride 1024
        instride = 1024;
        outbase = (size_t)(nc * 64) * 1024 + kc * 128;
        outp = WOT;
    }

    // read phase: [128 r][64 c] tile -> lds[c*129 + r]
    const int r0 = tid >> 4;                  // 0..15
    const int c4 = (tid & 15) * 4;            // 0,4,..,60
    #pragma unroll
    for (int cc = 0; cc < 8; ++cc) {
        const int r = cc * 16 + r0;
        float4 f = *(const float4*)&src[(size_t)r * instride + c4];
        lds[(c4 + 0) * 129 + r] = f.x * scale;
        lds[(c4 + 1) * 129 + r] = f.y * scale;
        lds[(c4 + 2) * 129 + r] = f.z * scale;
        lds[(c4 + 3) * 129 + r] = f.w * scale;
    }
    __syncthreads();

    // write phase: 64 out-rows (c), 128 bf16 each
    const int c = tid >> 2;                   // 0..63
    const int s = tid & 3;                    // 0..3
    #pragma unroll
    for (int j = 0; j < 4; ++j) {
        bf16x8 v;
        #pragma unroll
        for (int e = 0; e < 8; ++e)
            v[e] = f2bf(lds[c * 129 + s * 32 + j * 8 + e]);
        *(bf16x8*)&outp[outbase + (size_t)c * 1024 + s * 32 + j * 8] = v;
    }
}

// ---------------------------------------------------------------------------
// 2-phase GEMM (kept for the out projection): C = A @ Bt^T, fp32 C.
template<int CMODE, int BN>
__global__ __launch_bounds__(256) void gemm_bt(
    const unsigned short* __restrict__ A,
    const unsigned short* __restrict__ Bt,
    void* __restrict__ Cv,
    unsigned short* __restrict__ VT,
    int M, int N, int K, int ldc)
{
    __shared__ __align__(16) unsigned short As[2][128 * 32];
    __shared__ __align__(16) unsigned short Bs[2][BN * 32];

    // T1 swizzle (bijective: grid size divisible by 8)
    const int flat = blockIdx.y * gridDim.x + blockIdx.x;
    const int cpx  = (gridDim.x * gridDim.y) >> 3;
    const int swz  = (flat & 7) * cpx + (flat >> 3);
    const int m0 = (swz / gridDim.x) * 128;
    const int n0 = (swz % gridDim.x) * BN;

    const int tid  = threadIdx.x;
    const int w    = tid >> 6, lane = tid & 63;
    const int q4   = lane >> 4, lr  = lane & 15;
    constexpr int MI = (BN == 128) ? 4 : 2;
    const int rowBase = (BN == 128) ? (w >> 1) * 64 : w * 32;
    const int colBase = (BN == 128) ? (w & 1) * 64 : 0;

    const int ch   = tid & 3;
    const int row0 = tid >> 2;
    const int ldsOff = w * 512;   // halfwords; HW adds lane*16B

    const unsigned short* aP0 = &A [(size_t)(m0 + row0)      * K + ch * 8];
    const unsigned short* aP1 = &A [(size_t)(m0 + row0 + 64) * K + ch * 8];
    const unsigned short* bP0 = &Bt[(size_t)(n0 + row0)      * K + ch * 8];
    const unsigned short* bP1 = (BN == 128)
        ? &Bt[(size_t)(n0 + row0 + 64) * K + ch * 8] : nullptr;

    auto dma = [&](int buf, int k0) {
        gload_lds16(aP0 + k0, &As[buf][ldsOff]);
        gload_lds16(aP1 + k0, &As[buf][2048 + ldsOff]);
        gload_lds16(bP0 + k0, &Bs[buf][ldsOff]);
        if (BN == 128)
            gload_lds16(bP1 + k0, &Bs[buf][2048 + ldsOff]);
    };

    f32x4 acc[MI][4] = {};
    dma(0, 0);
    int cur = 0;

    for (int k0 = 0; k0 < K; k0 += 32) {
        __syncthreads();                          // drains DMA(k0) -> buf[cur] ready
        if (k0 + 32 < K) dma(cur ^ 1, k0 + 32);   // in flight during compute

        bf16x8 af[MI], bfv[4];
        #pragma unroll
        for (int i = 0; i < MI; ++i)
            af[i] = *(const bf16x8*)&As[cur][(rowBase + i * 16 + lr) * 32 + q4 * 8];
        #pragma unroll
        for (int j = 0; j < 4; ++j)
            bfv[j] = *(const bf16x8*)&Bs[cur][(colBase + j * 16 + lr) * 32 + q4 * 8];
        #pragma unroll
        for (int i = 0; i < MI; ++i)
            #pragma unroll
            for (int j = 0; j < 4; ++j)
                acc[i][j] = __builtin_amdgcn_mfma_f32_16x16x32_bf16(af[i], bfv[j], acc[i][j], 0, 0, 0);
        cur ^= 1;
    }

    #pragma unroll
    for (int i = 0; i < MI; ++i) {
        const int row = m0 + rowBase + i * 16 + q4 * 4;
        #pragma unroll
        for (int j = 0; j < 4; ++j) {
            const int col = n0 + colBase + j * 16 + lr;
            if (CMODE == 0) {
                float* C = (float*)Cv;
                #pragma unroll
                for (int p = 0; p < 4; ++p)
                    C[(size_t)(row + p) * ldc + col] = acc[i][j][p];
            } else {
                if (col < 2048) {
                    unsigned short* C = (unsigned short*)Cv;
                    #pragma unroll
                    for (int p = 0; p < 4; ++p)
                        C[(size_t)(row + p) * 2048 + col] = f2bf(acc[i][j][p]);
                } else {
                    const int c2 = col - 2048;
                    const int hh = c2 >> 6, dd = c2 & 63;
                    const int bb = row >> 11, ss = row & 2047;
                    ushortx4 v;
                    #pragma unroll
                    for (int p = 0; p < 4; ++p) v[p] = f2bf(acc[i][j][p]);
                    *(ushortx4*)&VT[((size_t)(bb * 16 + hh) * 64 + dd) * 2048 + ss] = v;
                }
            }
        }
    }
}

// ---------------------------------------------------------------------------
// R19 QKV GEMM: 256x256 tile, BK=64, 512 threads (8 waves 2Mx4N, 128x64 each),
// double-buffered 128KB LDS.  4 phases per K-tile; each phase stages ONE
// half-tile (2 gload_lds/thread) of tile t+1, halves ordered [B0,B1,A0,A1];
// counted vmcnt(2) only at phase 0 -- loads never drain to 0 in the loop.
// Epilogue: QK bf16 region (n0<2048) + transposed VT region (n0>=2048).
__global__ __launch_bounds__(512, 2) void gemm_qkv8(
    const unsigned short* __restrict__ A,    // XB [8192][1024]
    const unsigned short* __restrict__ Bt,   // WQKVT [3072][1024]
    unsigned short* __restrict__ QK,         // [8192][2048]
    unsigned short* __restrict__ VT)
{
    constexpr int K = 1024;
    __shared__ __align__(16) unsigned short As[32768];   // 2 buf x 2 half x 8192
    __shared__ __align__(16) unsigned short Bs[32768];

    // T1 XCD-chunked swizzle: 384 blocks, 48 per XCD
    const int flat = blockIdx.y * 12 + blockIdx.x;
    const int swz  = (flat & 7) * 48 + (flat >> 3);
    const int m0 = (swz / 12) * 256;
    const int n0 = (swz % 12) * 256;

    const int tid  = threadIdx.x;
    const int w    = tid >> 6, lane = tid & 63;
    const int q4   = lane >> 4, lr  = lane & 15;
    const int wr   = w >> 2, wc = w & 3;      // wave tile: rows wr*128, cols wc*64

    const unsigned short* pA = A  + (size_t)(m0 + (tid >> 3)) * K + (tid & 7) * 8;
    const unsigned short* pB = Bt + (size_t)(n0 + (tid >> 3)) * K + (tid & 7) * 8;
    const int woff = w * 512;                 // halfwords; HW adds lane*16B

    // half h (0..63): tile t=h>>2, kind h&3: 0=B0 1=B1 2=A0 3=A1
    auto stage = [&](int h) {
        if (h >= 64) return;
        const int t = h >> 2, kind = h & 3, buf = t & 1;
        if (kind >= 2) {
            const int i = kind - 2;
            const unsigned short* s = pA + (size_t)(i * 128) * K + t * 64;
            unsigned short* d = &As[buf * 16384 + i * 8192 + woff];
            gload_lds16(s, d);
            gload_lds16(s + (size_t)64 * K, d + 4096);
        } else {
            const unsigned short* s = pB + (size_t)(kind * 128) * K + t * 64;
            unsigned short* d = &Bs[buf * 16384 + kind * 8192 + woff];
            gload_lds16(s, d);
            gload_lds16(s + (size_t)64 * K, d + 4096);
        }
    };

    // prologue: tile 0's 4 halves (8 loads/thread, in flight)
    stage(0); stage(1); stage(2); stage(3);

    f32x4 acc[8][4] = {};

    for (int t = 0; t < 16; ++t) {
        const int buf = t & 1;
        const unsigned short* Ab = &As[buf * 16384 + wr * 8192];
        const unsigned short* Bb = &Bs[buf * 16384 + (wc >> 1) * 8192];
        const int brow = (wc & 1) * 64;
        bf16x8 bf[4][2];

        // ---- phase 0: gate tile t, load B frags + m-group 0 ----
        stage(4 * t + 4);                      // B0 of tile t+1 (disjoint from
                                               // straggler phase-3 A reads)
        asm volatile("s_waitcnt vmcnt(2)" ::: "memory");   // tile t fully landed
        __builtin_amdgcn_s_barrier();
        #pragma unroll
        for (int n = 0; n < 4; ++n)
            #pragma unroll
            for (int ks = 0; ks < 2; ++ks)
                bf[n][ks] = *(const bf16x8*)&Bb[(brow + n * 16 + lr) * 64 + ks * 32 + q4 * 8];
        {
            bf16x8 af[2][2];
            #pragma unroll
            for (int mm = 0; mm < 2; ++mm)
                #pragma unroll
                for (int ks = 0; ks < 2; ++ks)
                    af[mm][ks] = *(const bf16x8*)&Ab[(mm * 16 + lr) * 64 + ks * 32 + q4 * 8];
            __builtin_amdgcn_s_setprio(1);
            #pragma unroll
            for (int mm = 0; mm < 2; ++mm)
                #pragma unroll
                for (int n = 0; n < 4; ++n)
                    #pragma unroll
                    for (int ks = 0; ks < 2; ++ks)
                        acc[mm][n] = __builtin_amdgcn_mfma_f32_16x16x32_bf16(af[mm][ks], bf[n][ks], acc[mm][n], 0, 0, 0);
            __builtin_amdgcn_s_setprio(0);
        }

        // ---- phases 1..3: m-groups 1..3 ----
        #pragma unroll
        for (int p = 1; p < 4; ++p) {
            stage(4 * t + 4 + p);
            __builtin_amdgcn_s_barrier();
            bf16x8 af[2][2];
            #pragma unroll
            for (int mm = 0; mm < 2; ++mm)
                #pragma unroll
                for (int ks = 0; ks < 2; ++ks)
                    af[mm][ks] = *(const bf16x8*)&Ab[(p * 32 + mm * 16 + lr) * 64 + ks * 32 + q4 * 8];
            __builtin_amdgcn_s_setprio(1);
            #pragma unroll
            for (int mm = 0; mm < 2; ++mm)
                #pragma unroll
                for (int n = 0; n < 4; ++n)
                    #pragma unroll
                    for (int ks = 0; ks < 2; ++ks)
                        acc[p * 2 + mm][n] = __builtin_amdgcn_mfma_f32_16x16x32_bf16(af[mm][ks], bf[n][ks], acc[p * 2 + mm][n], 0, 0, 0);
            __builtin_amdgcn_s_setprio(0);
        }
    }

    // epilogue (same store forms as R13)
    #pragma unroll
    for (int m = 0; m < 8; ++m) {
        const int row = m0 + wr * 128 + m * 16 + q4 * 4;
        #pragma unroll
        for (int n = 0; n < 4; ++n) {
            const int col = n0 + wc * 64 + n * 16 + lr;
            if (col < 2048) {
                #pragma unroll
                for (int p = 0; p < 4; ++p)
                    QK[(size_t)(row + p) * 2048 + col] = f2bf(acc[m][n][p]);
            } else {
                const int c2 = col - 2048;
                const int hh = c2 >> 6, dd = c2 & 63;
                const int bb = row >> 11, ss = row & 2047;
                ushortx4 v;
                #pragma unroll
                for (int p = 0; p < 4; ++p) v[p] = f2bf(acc[m][n][p]);
                *(ushortx4*)&VT[((size_t)(bb * 16 + hh) * 64 + dd) * 2048 + ss] = v;
            }
        }
    }
}

// ---------------------------------------------------------------------------
// Flash attention, transposed-P scheme (R18 config, unchanged).
__global__ __launch_bounds__(256, 4) void attn_flash(
    const unsigned short* __restrict__ QK,
    const unsigned short* __restrict__ VT,
    unsigned short* __restrict__ HC)        // [8192][1024] bf16
{
    const int bh  = blockIdx.x;   // b*16+h  (fastest dim -> XCD-pinned K/V reuse)
    const int qb  = blockIdx.y;   // 0..15
    const int b   = bh >> 4, h = bh & 15;
    const int tid = threadIdx.x;
    const int w   = tid >> 6, lane = tid & 63;
    const int q4  = lane >> 4, lr  = lane & 15;

    __shared__ __align__(16) unsigned short Ks [2][64 * 64];   // [key][dk] swizzled
    __shared__ __align__(16) unsigned short Vts[2][64 * 64];   // [d][key]  swizzled

    // DMA mapping: round R covers rows R*32+(tid>>3), chunk slot tid&7.
    const int drow   = tid >> 3;                       // 0..31
    const int gchunk = (tid & 7) ^ (drow & 7);         // global chunk for slot tid&7
    const unsigned short* Kg = QK + (size_t)(b * 2048) * 2048 + 1024 + h * 64;
    const unsigned short* Vg = VT + (size_t)bh * 64 * 2048;
    // running global pointers (advance per 64-key tile)
    const unsigned short* kP0 = Kg + (size_t)(drow)      * 2048 + gchunk * 8;
    const unsigned short* kP1 = Kg + (size_t)(drow + 32) * 2048 + gchunk * 8;
    const unsigned short* vP0 = Vg + (size_t)(drow)      * 2048 + gchunk * 8;
    const unsigned short* vP1 = Vg + (size_t)(drow + 32) * 2048 + gchunk * 8;
    const int ldsOff = w * 512;                        // halfwords; +lane*8 by HW

    auto dma = [&](int buf, int t) {
        gload_lds16(kP0 + (size_t)t * 131072, &Ks [buf][ldsOff]);
        gload_lds16(kP1 + (size_t)t * 131072, &Ks [buf][2048 + ldsOff]);
        gload_lds16(vP0 + t * 64,             &Vts[buf][ldsOff]);
        gload_lds16(vP1 + t * 64,             &Vts[buf][2048 + ldsOff]);
    };

    dma(0, 0);

    const int qrow0 = b * 2048 + qb * 128 + w * 32;
    bf16x8 qf[2][2];   // B-frag of Q^T == A-frag of Q: Q[q=lr][dk=c*32+q4*8+j]
    #pragma unroll
    for (int u = 0; u < 2; ++u)
        #pragma unroll
        for (int c = 0; c < 2; ++c)
            qf[u][c] = *(const bf16x8*)&QK[(size_t)(qrow0 + u * 16 + lr) * 2048
                                           + h * 64 + c * 32 + q4 * 8];

    const int lr7 = lr & 7;

    // ones A-fragment (bf16 1.0) for denominator row-sum MFMA
    const short oneb = (short)0x3F80;
    const bf16x8 onesf = { oneb, oneb, oneb, oneb, oneb, oneb, oneb, oneb };

    f32x4 o[2][4] = {};      // O^T[d=jd*16+q4*4+p][q=u*16+lr]
    f32x4 lsum[2] = {};      // denominator: all rows equal = sum_k P^T[k][q=lr]
    int cur = 0;

    for (int t = 0; t < 32; ++t) {
        __syncthreads();                       // drains DMA(t) -> buf[cur] ready
        if (t + 1 < 32) dma(cur ^ 1, t + 1);   // in flight during compute

        #pragma unroll
        for (int kc = 0; kc < 2; ++kc) {
            // --- S^T for this 32-key chunk (2 mt subtiles) ---
            unsigned int pk[2][2][2];          // packed P^T words [u][ml][i]
            #pragma unroll
            for (int ml = 0; ml < 2; ++ml) {
                const int mt = kc * 2 + ml;
                f32x4 st[2] = {};
                __builtin_amdgcn_s_setprio(1);
                #pragma unroll
                for (int c = 0; c < 2; ++c) {
                    const int slot = (c * 4 + q4) ^ lr7;
                    bf16x8 kf = *(const bf16x8*)&Ks[cur][(mt * 16 + lr) * 64 + slot * 8];
                    #pragma unroll
                    for (int u = 0; u < 2; ++u)
                        st[u] = __builtin_amdgcn_mfma_f32_16x16x32_bf16(kf, qf[u][c], st[u], 0, 0, 0);
                }
                __builtin_amdgcn_s_setprio(0);
                #pragma unroll
                for (int u = 0; u < 2; ++u) {
                    float e0 = __builtin_amdgcn_exp2f(st[u][0]);
                    float e1 = __builtin_amdgcn_exp2f(st[u][1]);
                    float e2 = __builtin_amdgcn_exp2f(st[u][2]);
                    float e3 = __builtin_amdgcn_exp2f(st[u][3]);
                    pk[u][ml][0] = pack_bf2(e1, e0);
                    pk[u][ml][1] = pack_bf2(e3, e2);
                }
            }

            // --- lane exchange P^T -> PV B-frags (pure VALU permlane) ---
            bf16x8 pb[2];
            #pragma unroll
            for (int u = 0; u < 2; ++u) {
                uint2v a0 = __builtin_amdgcn_permlane32_swap(pk[u][0][0], pk[u][1][0], false, false);
                uint2v b0 = __builtin_amdgcn_permlane16_swap(a0[0], a0[1], false, false);
                uint2v a1 = __builtin_amdgcn_permlane32_swap(pk[u][0][1], pk[u][1][1], false, false);
                uint2v b1 = __builtin_amdgcn_permlane16_swap(a1[0], a1[1], false, false);
                int4 wv;
                wv.x = (int)b0[0];
                wv.y = (int)b1[0];
                wv.z = (int)b0[1];
                wv.w = (int)b1[1];
                pb[u] = *(bf16x8*)&wv;
            }

            // --- PV: O^T += V^T · P^T  (+ denominator row-sum) ---
            __builtin_amdgcn_s_setprio(1);
            #pragma unroll
            for (int u = 0; u < 2; ++u)
                lsum[u] = __builtin_amdgcn_mfma_f32_16x16x32_bf16(onesf, pb[u], lsum[u], 0, 0, 0);
            #pragma unroll
            for (int jd = 0; jd < 4; ++jd) {
                const int slot = (kc * 4 + q4) ^ lr7;
                bf16x8 vf = *(const bf16x8*)&Vts[cur][(jd * 16 + lr) * 64 + slot * 8];
                #pragma unroll
                for (int u = 0; u < 2; ++u)
                    o[u][jd] = __builtin_amdgcn_mfma_f32_16x16x32_bf16(vf, pb[u], o[u][jd], 0, 0, 0);
            }
            __builtin_amdgcn_s_setprio(0);
        }
        cur ^= 1;
    }

    #pragma unroll
    for (int u = 0; u < 2; ++u) {
        const float inv = __builtin_amdgcn_rcpf(lsum[u][0]);
        const size_t rowO = (size_t)(qrow0 + u * 16 + lr);
        #pragma unroll
        for (int jd = 0; jd < 4; ++jd) {
            ushortx4 v;
            #pragma unroll
            for (int p = 0; p < 4; ++p)
                v[p] = f2bf(o[u][jd][p] * inv);
            *(ushortx4*)&HC[rowO * 1024 + h * 64 + jd * 16 + q4 * 4] = v;
        }
    }
}

// ---------------------------------------------------------------------------
extern "C" void kernel_launch(void* const* d_in, const int* in_sizes, int n_in,
                              void* d_out, int out_size, void* d_ws, size_t ws_size,
                              hipStream_t stream)
{
    const float* x  = (const float*)d_in[0];
    const float* Wq = (const float*)d_in[1];
    const float* Wk = (const float*)d_in[2];
    const float* Wv = (const float*)d_in[3];
    const float* Wo = (const float*)d_in[4];
    float* out = (float*)d_out;

    char* ws = (char*)d_ws;
    unsigned short* XB    = (unsigned short*)(ws);              // 16777216 (aliases HC)
    unsigned short* HC    = (unsigned short*)(ws);
    unsigned short* WQKVT = (unsigned short*)(ws + 16777216);   // 6291456
    unsigned short* WOT   = (unsigned short*)(ws + 23068672);   // 2097152
    unsigned short* QK    = (unsigned short*)(ws + 25165824);   // 33554432
    unsigned short* VT    = (unsigned short*)(ws + 58720256);   // 16777216
    // total ws: 75497472 B (~72 MiB)

    pack_all<<<4608, 256, 0, stream>>>(x, Wq, Wk, Wv, Wo, XB, WQKVT, WOT);
    gemm_qkv8<<<dim3(12, 32), 512, 0, stream>>>(XB, WQKVT, QK, VT);
    attn_flash<<<dim3(64, 16), 256, 0, stream>>>(QK, VT, HC);
    gemm_bt<0, 128><<<dim3(8, 64), 256, 0, stream>>>(HC, WOT, out, nullptr, 8192, 1024, 1024, 1024);
}

// Round 11
// 275.811 us; speedup vs baseline: 1.0299x; 1.0299x over previous
//
#include <hip/hip_runtime.h>

// MultiHeadAttention: B=4, S=2048, D=1024, H=16, dk=dv=64.
// Inputs fp32, output fp32; compute bf16 MFMA.
// R9: attention computes S^T = K·Q^T so P^T exits MFMA in a layout reachable
// from the PV B-operand by a pure lane permutation -- no P LDS round-trip.
// R10: attn VALU diet: builtin exp2, ones-MFMA denominator, v_perm pack.
// R12: ds_bpermute -> permlane32/16_swap: conflicts 8.4M->0, attn 112->83us.
// R13: gemm_bt double-buffered, 1 barrier/K-step.
// R16: pack_all LDS-transpose (-19us).  R18: QKV XCD swizzle; attn setprio.
// R19: QKV 8-phase (T3+T4+T5) REGRESSED 96.5us: BK=64 rows = 128B stride and
// I dropped the XOR swizzle -> 14.16M bank conflicts, MfmaUtil 20.7 (T2 is
// the prerequisite for T3/T4 to pay).
// R20: add attn-proven swizzle to gemm_qkv8: pre-swizzled global source
// chunk (tid&7)^(row&7) (gload_lds dest stays linear, m173 pattern) +
// swizzled read slot (ks*4+q4)^(lr&7).  Identical tile geometry in attn
// measures 0 conflicts.  Everything else unchanged.

typedef __attribute__((ext_vector_type(8))) short bf16x8;   // 8 bf16 = 4 VGPRs
typedef __attribute__((ext_vector_type(4))) float f32x4;
typedef __attribute__((ext_vector_type(4))) unsigned short ushortx4;
typedef __attribute__((ext_vector_type(2))) unsigned int uint2v;

__device__ __forceinline__ unsigned short f2bf(float x) {   // RNE
    unsigned int u = __float_as_uint(x);
    u += 0x7FFFu + ((u >> 16) & 1u);
    return (unsigned short)(u >> 16);
}
// pack two floats as truncated bf16 pair: [hi.bf16 : lo.bf16] -- v_perm_b32
__device__ __forceinline__ unsigned int pack_bf2(float hi, float lo) {
    return __builtin_amdgcn_perm(__float_as_uint(hi), __float_as_uint(lo), 0x07060302u);
}

// async 16B global -> LDS (lds dest wave-uniform; HW adds lane*16)
__device__ __forceinline__ void gload_lds16(const unsigned short* g, unsigned short* lds) {
    __builtin_amdgcn_global_load_lds(
        (const __attribute__((address_space(1))) unsigned int*)g,
        (__attribute__((address_space(3))) unsigned int*)lds,
        16, 0, 0);
}

// ---------------------------------------------------------------------------
// One merged pack kernel. Sections by blockIdx.x:
//  [0,4096):      XB  = bf16(x)                       (coalesced)
//  [4096,4480):   WQKVT[n][d]  via LDS-transposed tiles (Wq scaled)
//  [4480,4608):   WOT[n][k] = Wo[k][n] via LDS-transposed tiles
__global__ __launch_bounds__(256) void pack_all(
    const float* __restrict__ x,
    const float* __restrict__ Wq,
    const float* __restrict__ Wk,
    const float* __restrict__ Wv,
    const float* __restrict__ Wo,
    unsigned short* __restrict__ XB,
    unsigned short* __restrict__ WQKVT,
    unsigned short* __restrict__ WOT)
{
    const int bid = blockIdx.x;
    const int tid = threadIdx.x;
    if (bid < 4096) {
        bf16x8 v;
        size_t base = ((size_t)bid * 256 + tid) * 8;
        float4 f0 = *(const float4*)&x[base];
        float4 f1 = *(const float4*)&x[base + 4];
        v[0] = f2bf(f0.x); v[1] = f2bf(f0.y); v[2] = f2bf(f0.z); v[3] = f2bf(f0.w);
        v[4] = f2bf(f1.x); v[5] = f2bf(f1.y); v[6] = f2bf(f1.z); v[7] = f2bf(f1.w);
        *(bf16x8*)&XB[base] = v;
        return;
    }

    __shared__ float lds[64 * 129];
    const float* src;
    size_t outbase;
    float scale = 1.0f;
    int instride;
    unsigned short* outp;
    if (bid < 4480) {
        const int widx = bid - 4096;
        const int part = widx >> 7;           // 0..2 (q,k,v)
        const int rem  = widx & 127;
        const int h    = rem >> 3;            // 0..15
        const int chunk = rem & 7;            // d-chunk of 128
        const float* W = (part == 0) ? Wq : ((part == 1) ? Wk : Wv);
        src = W + h * 65536 + chunk * 8192;   // [128 d][64 kk], row stride 64
        instride = 64;
        outbase = ((size_t)(part * 1024 + h * 64)) * 1024 + chunk * 128;
        if (part == 0) scale = 0.125f * 1.44269504088896f;
        outp = WQKVT;
    } else {
        const int oidx = bid - 4480;
        const int kc = oidx >> 4;             // k-chunk of 128 (0..7)
        const int nc = oidx & 15;             // n-chunk of 64  (0..15)
        src = Wo + (size_t)kc * 128 * 1024 + nc * 64;   // [128 k][64 n], stride 1024
        instride = 1024;
        outbase = (size_t)(nc * 64) * 1024 + kc * 128;
        outp = WOT;
    }

    // read phase: [128 r][64 c] tile -> lds[c*129 + r]
    const int r0 = tid >> 4;                  // 0..15
    const int c4 = (tid & 15) * 4;            // 0,4,..,60
    #pragma unroll
    for (int cc = 0; cc < 8; ++cc) {
        const int r = cc * 16 + r0;
        float4 f = *(const float4*)&src[(size_t)r * instride + c4];
        lds[(c4 + 0) * 129 + r] = f.x * scale;
        lds[(c4 + 1) * 129 + r] = f.y * scale;
        lds[(c4 + 2) * 129 + r] = f.z * scale;
        lds[(c4 + 3) * 129 + r] = f.w * scale;
    }
    __syncthreads();

    // write phase: 64 out-rows (c), 128 bf16 each
    const int c = tid >> 2;                   // 0..63
    const int s = tid & 3;                    // 0..3
    #pragma unroll
    for (int j = 0; j < 4; ++j) {
        bf16x8 v;
        #pragma unroll
        for (int e = 0; e < 8; ++e)
            v[e] = f2bf(lds[c * 129 + s * 32 + j * 8 + e]);
        *(bf16x8*)&outp[outbase + (size_t)c * 1024 + s * 32 + j * 8] = v;
    }
}

// ---------------------------------------------------------------------------
// 2-phase GEMM (kept for the out projection): C = A @ Bt^T, fp32 C.
template<int CMODE, int BN>
__global__ __launch_bounds__(256) void gemm_bt(
    const unsigned short* __restrict__ A,
    const unsigned short* __restrict__ Bt,
    void* __restrict__ Cv,
    unsigned short* __restrict__ VT,
    int M, int N, int K, int ldc)
{
    __shared__ __align__(16) unsigned short As[2][128 * 32];
    __shared__ __align__(16) unsigned short Bs[2][BN * 32];

    // T1 swizzle (bijective: grid size divisible by 8)
    const int flat = blockIdx.y * gridDim.x + blockIdx.x;
    const int cpx  = (gridDim.x * gridDim.y) >> 3;
    const int swz  = (flat & 7) * cpx + (flat >> 3);
    const int m0 = (swz / gridDim.x) * 128;
    const int n0 = (swz % gridDim.x) * BN;

    const int tid  = threadIdx.x;
    const int w    = tid >> 6, lane = tid & 63;
    const int q4   = lane >> 4, lr  = lane & 15;
    constexpr int MI = (BN == 128) ? 4 : 2;
    const int rowBase = (BN == 128) ? (w >> 1) * 64 : w * 32;
    const int colBase = (BN == 128) ? (w & 1) * 64 : 0;

    const int ch   = tid & 3;
    const int row0 = tid >> 2;
    const int ldsOff = w * 512;   // halfwords; HW adds lane*16B

    const unsigned short* aP0 = &A [(size_t)(m0 + row0)      * K + ch * 8];
    const unsigned short* aP1 = &A [(size_t)(m0 + row0 + 64) * K + ch * 8];
    const unsigned short* bP0 = &Bt[(size_t)(n0 + row0)      * K + ch * 8];
    const unsigned short* bP1 = (BN == 128)
        ? &Bt[(size_t)(n0 + row0 + 64) * K + ch * 8] : nullptr;

    auto dma = [&](int buf, int k0) {
        gload_lds16(aP0 + k0, &As[buf][ldsOff]);
        gload_lds16(aP1 + k0, &As[buf][2048 + ldsOff]);
        gload_lds16(bP0 + k0, &Bs[buf][ldsOff]);
        if (BN == 128)
            gload_lds16(bP1 + k0, &Bs[buf][2048 + ldsOff]);
    };

    f32x4 acc[MI][4] = {};
    dma(0, 0);
    int cur = 0;

    for (int k0 = 0; k0 < K; k0 += 32) {
        __syncthreads();                          // drains DMA(k0) -> buf[cur] ready
        if (k0 + 32 < K) dma(cur ^ 1, k0 + 32);   // in flight during compute

        bf16x8 af[MI], bfv[4];
        #pragma unroll
        for (int i = 0; i < MI; ++i)
            af[i] = *(const bf16x8*)&As[cur][(rowBase + i * 16 + lr) * 32 + q4 * 8];
        #pragma unroll
        for (int j = 0; j < 4; ++j)
            bfv[j] = *(const bf16x8*)&Bs[cur][(colBase + j * 16 + lr) * 32 + q4 * 8];
        #pragma unroll
        for (int i = 0; i < MI; ++i)
            #pragma unroll
            for (int j = 0; j < 4; ++j)
                acc[i][j] = __builtin_amdgcn_mfma_f32_16x16x32_bf16(af[i], bfv[j], acc[i][j], 0, 0, 0);
        cur ^= 1;
    }

    #pragma unroll
    for (int i = 0; i < MI; ++i) {
        const int row = m0 + rowBase + i * 16 + q4 * 4;
        #pragma unroll
        for (int j = 0; j < 4; ++j) {
            const int col = n0 + colBase + j * 16 + lr;
            if (CMODE == 0) {
                float* C = (float*)Cv;
                #pragma unroll
                for (int p = 0; p < 4; ++p)
                    C[(size_t)(row + p) * ldc + col] = acc[i][j][p];
            } else {
                if (col < 2048) {
                    unsigned short* C = (unsigned short*)Cv;
                    #pragma unroll
                    for (int p = 0; p < 4; ++p)
                        C[(size_t)(row + p) * 2048 + col] = f2bf(acc[i][j][p]);
                } else {
                    const int c2 = col - 2048;
                    const int hh = c2 >> 6, dd = c2 & 63;
                    const int bb = row >> 11, ss = row & 2047;
                    ushortx4 v;
                    #pragma unroll
                    for (int p = 0; p < 4; ++p) v[p] = f2bf(acc[i][j][p]);
                    *(ushortx4*)&VT[((size_t)(bb * 16 + hh) * 64 + dd) * 2048 + ss] = v;
                }
            }
        }
    }
}

// ---------------------------------------------------------------------------
// R20 QKV GEMM: 256x256 tile, BK=64, 512 threads (8 waves 2Mx4N, 128x64 each),
// double-buffered 128KB LDS, 4 phases/tile, counted vmcnt(2) at phase 0 only.
// XOR swizzle (T2): global source chunk (tid&7)^(row&7) pre-swizzled so the
// linear gload_lds dest yields LDS[row][slot] = chunk slot^(row&7); reads use
// slot = (ks*4+q4)^(lr&7).  Same scheme as attn (measured 0 conflicts).
__global__ __launch_bounds__(512, 2) void gemm_qkv8(
    const unsigned short* __restrict__ A,    // XB [8192][1024]
    const unsigned short* __restrict__ Bt,   // WQKVT [3072][1024]
    unsigned short* __restrict__ QK,         // [8192][2048]
    unsigned short* __restrict__ VT)
{
    constexpr int K = 1024;
    __shared__ __align__(16) unsigned short As[32768];   // 2 buf x 2 half x 8192
    __shared__ __align__(16) unsigned short Bs[32768];

    // T1 XCD-chunked swizzle: 384 blocks, 48 per XCD
    const int flat = blockIdx.y * 12 + blockIdx.x;
    const int swz  = (flat & 7) * 48 + (flat >> 3);
    const int m0 = (swz / 12) * 256;
    const int n0 = (swz % 12) * 256;

    const int tid  = threadIdx.x;
    const int w    = tid >> 6, lane = tid & 63;
    const int q4   = lane >> 4, lr  = lane & 15;
    const int lr7  = lr & 7;
    const int wr   = w >> 2, wc = w & 3;      // wave tile: rows wr*128, cols wc*64

    // pre-swizzled global source (T2 via m173: dest linear, source permuted)
    const int srow = tid >> 3;                // 0..63 (row within half, mod 64)
    const int gch  = (tid & 7) ^ (srow & 7);  // XOR key invariant: rows step by 64/128
    const unsigned short* pA = A  + (size_t)(m0 + srow) * K + gch * 8;
    const unsigned short* pB = Bt + (size_t)(n0 + srow) * K + gch * 8;
    const int woff = w * 512;                 // halfwords; HW adds lane*16B

    // half h (0..63): tile t=h>>2, kind h&3: 0=B0 1=B1 2=A0 3=A1
    auto stage = [&](int h) {
        if (h >= 64) return;
        const int t = h >> 2, kind = h & 3, buf = t & 1;
        if (kind >= 2) {
            const int i = kind - 2;
            const unsigned short* s = pA + (size_t)(i * 128) * K + t * 64;
            unsigned short* d = &As[buf * 16384 + i * 8192 + woff];
            gload_lds16(s, d);
            gload_lds16(s + (size_t)64 * K, d + 4096);
        } else {
            const unsigned short* s = pB + (size_t)(kind * 128) * K + t * 64;
            unsigned short* d = &Bs[buf * 16384 + kind * 8192 + woff];
            gload_lds16(s, d);
            gload_lds16(s + (size_t)64 * K, d + 4096);
        }
    };

    // prologue: tile 0's 4 halves (8 loads/thread, in flight)
    stage(0); stage(1); stage(2); stage(3);

    f32x4 acc[8][4] = {};

    for (int t = 0; t < 16; ++t) {
        const int buf = t & 1;
        const unsigned short* Ab = &As[buf * 16384 + wr * 8192];
        const unsigned short* Bb = &Bs[buf * 16384 + (wc >> 1) * 8192];
        const int brow = (wc & 1) * 64;
        bf16x8 bf[4][2];

        // ---- phase 0: gate tile t, load B frags + m-group 0 ----
        stage(4 * t + 4);                      // B0 of tile t+1 (disjoint from
                                               // straggler phase-3 A reads)
        asm volatile("s_waitcnt vmcnt(2)" ::: "memory");   // tile t fully landed
        __builtin_amdgcn_s_barrier();
        #pragma unroll
        for (int n = 0; n < 4; ++n)
            #pragma unroll
            for (int ks = 0; ks < 2; ++ks) {
                const int slot = (ks * 4 + q4) ^ lr7;
                bf[n][ks] = *(const bf16x8*)&Bb[(brow + n * 16 + lr) * 64 + slot * 8];
            }
        {
            bf16x8 af[2][2];
            #pragma unroll
            for (int mm = 0; mm < 2; ++mm)
                #pragma unroll
                for (int ks = 0; ks < 2; ++ks) {
                    const int slot = (ks * 4 + q4) ^ lr7;
                    af[mm][ks] = *(const bf16x8*)&Ab[(mm * 16 + lr) * 64 + slot * 8];
                }
            __builtin_amdgcn_s_setprio(1);
            #pragma unroll
            for (int mm = 0; mm < 2; ++mm)
                #pragma unroll
                for (int n = 0; n < 4; ++n)
                    #pragma unroll
                    for (int ks = 0; ks < 2; ++ks)
                        acc[mm][n] = __builtin_amdgcn_mfma_f32_16x16x32_bf16(af[mm][ks], bf[n][ks], acc[mm][n], 0, 0, 0);
            __builtin_amdgcn_s_setprio(0);
        }

        // ---- phases 1..3: m-groups 1..3 ----
        #pragma unroll
        for (int p = 1; p < 4; ++p) {
            stage(4 * t + 4 + p);
            __builtin_amdgcn_s_barrier();
            bf16x8 af[2][2];
            #pragma unroll
            for (int mm = 0; mm < 2; ++mm)
                #pragma unroll
                for (int ks = 0; ks < 2; ++ks) {
                    const int slot = (ks * 4 + q4) ^ lr7;
                    af[mm][ks] = *(const bf16x8*)&Ab[(p * 32 + mm * 16 + lr) * 64 + slot * 8];
                }
            __builtin_amdgcn_s_setprio(1);
            #pragma unroll
            for (int mm = 0; mm < 2; ++mm)
                #pragma unroll
                for (int n = 0; n < 4; ++n)
                    #pragma unroll
                    for (int ks = 0; ks < 2; ++ks)
                        acc[p * 2 + mm][n] = __builtin_amdgcn_mfma_f32_16x16x32_bf16(af[mm][ks], bf[n][ks], acc[p * 2 + mm][n], 0, 0, 0);
            __builtin_amdgcn_s_setprio(0);
        }
    }

    // epilogue (same store forms as R13)
    #pragma unroll
    for (int m = 0; m < 8; ++m) {
        const int row = m0 + wr * 128 + m * 16 + q4 * 4;
        #pragma unroll
        for (int n = 0; n < 4; ++n) {
            const int col = n0 + wc * 64 + n * 16 + lr;
            if (col < 2048) {
                #pragma unroll
                for (int p = 0; p < 4; ++p)
                    QK[(size_t)(row + p) * 2048 + col] = f2bf(acc[m][n][p]);
            } else {
                const int c2 = col - 2048;
                const int hh = c2 >> 6, dd = c2 & 63;
                const int bb = row >> 11, ss = row & 2047;
                ushortx4 v;
                #pragma unroll
                for (int p = 0; p < 4; ++p) v[p] = f2bf(acc[m][n][p]);
                *(ushortx4*)&VT[((size_t)(bb * 16 + hh) * 64 + dd) * 2048 + ss] = v;
            }
        }
    }
}

// ---------------------------------------------------------------------------
// Flash attention, transposed-P scheme (R18 config, unchanged).
__global__ __launch_bounds__(256, 4) void attn_flash(
    const unsigned short* __restrict__ QK,
    const unsigned short* __restrict__ VT,
    unsigned short* __restrict__ HC)        // [8192][1024] bf16
{
    const int bh  = blockIdx.x;   // b*16+h  (fastest dim -> XCD-pinned K/V reuse)
    const int qb  = blockIdx.y;   // 0..15
    const int b   = bh >> 4, h = bh & 15;
    const int tid = threadIdx.x;
    const int w   = tid >> 6, lane = tid & 63;
    const int q4  = lane >> 4, lr  = lane & 15;

    __shared__ __align__(16) unsigned short Ks [2][64 * 64];   // [key][dk] swizzled
    __shared__ __align__(16) unsigned short Vts[2][64 * 64];   // [d][key]  swizzled

    // DMA mapping: round R covers rows R*32+(tid>>3), chunk slot tid&7.
    const int drow   = tid >> 3;                       // 0..31
    const int gchunk = (tid & 7) ^ (drow & 7);         // global chunk for slot tid&7
    const unsigned short* Kg = QK + (size_t)(b * 2048) * 2048 + 1024 + h * 64;
    const unsigned short* Vg = VT + (size_t)bh * 64 * 2048;
    // running global pointers (advance per 64-key tile)
    const unsigned short* kP0 = Kg + (size_t)(drow)      * 2048 + gchunk * 8;
    const unsigned short* kP1 = Kg + (size_t)(drow + 32) * 2048 + gchunk * 8;
    const unsigned short* vP0 = Vg + (size_t)(drow)      * 2048 + gchunk * 8;
    const unsigned short* vP1 = Vg + (size_t)(drow + 32) * 2048 + gchunk * 8;
    const int ldsOff = w * 512;                        // halfwords; +lane*8 by HW

    auto dma = [&](int buf, int t) {
        gload_lds16(kP0 + (size_t)t * 131072, &Ks [buf][ldsOff]);
        gload_lds16(kP1 + (size_t)t * 131072, &Ks [buf][2048 + ldsOff]);
        gload_lds16(vP0 + t * 64,             &Vts[buf][ldsOff]);
        gload_lds16(vP1 + t * 64,             &Vts[buf][2048 + ldsOff]);
    };

    dma(0, 0);

    const int qrow0 = b * 2048 + qb * 128 + w * 32;
    bf16x8 qf[2][2];   // B-frag of Q^T == A-frag of Q: Q[q=lr][dk=c*32+q4*8+j]
    #pragma unroll
    for (int u = 0; u < 2; ++u)
        #pragma unroll
        for (int c = 0; c < 2; ++c)
            qf[u][c] = *(const bf16x8*)&QK[(size_t)(qrow0 + u * 16 + lr) * 2048
                                           + h * 64 + c * 32 + q4 * 8];

    const int lr7 = lr & 7;

    // ones A-fragment (bf16 1.0) for denominator row-sum MFMA
    const short oneb = (short)0x3F80;
    const bf16x8 onesf = { oneb, oneb, oneb, oneb, oneb, oneb, oneb, oneb };

    f32x4 o[2][4] = {};      // O^T[d=jd*16+q4*4+p][q=u*16+lr]
    f32x4 lsum[2] = {};      // denominator: all rows equal = sum_k P^T[k][q=lr]
    int cur = 0;

    for (int t = 0; t < 32; ++t) {
        __syncthreads();                       // drains DMA(t) -> buf[cur] ready
        if (t + 1 < 32) dma(cur ^ 1, t + 1);   // in flight during compute

        #pragma unroll
        for (int kc = 0; kc < 2; ++kc) {
            // --- S^T for this 32-key chunk (2 mt subtiles) ---
            unsigned int pk[2][2][2];          // packed P^T words [u][ml][i]
            #pragma unroll
            for (int ml = 0; ml < 2; ++ml) {
                const int mt = kc * 2 + ml;
                f32x4 st[2] = {};
                __builtin_amdgcn_s_setprio(1);
                #pragma unroll
                for (int c = 0; c < 2; ++c) {
                    const int slot = (c * 4 + q4) ^ lr7;
                    bf16x8 kf = *(const bf16x8*)&Ks[cur][(mt * 16 + lr) * 64 + slot * 8];
                    #pragma unroll
                    for (int u = 0; u < 2; ++u)
                        st[u] = __builtin_amdgcn_mfma_f32_16x16x32_bf16(kf, qf[u][c], st[u], 0, 0, 0);
                }
                __builtin_amdgcn_s_setprio(0);
                #pragma unroll
                for (int u = 0; u < 2; ++u) {
                    float e0 = __builtin_amdgcn_exp2f(st[u][0]);
                    float e1 = __builtin_amdgcn_exp2f(st[u][1]);
                    float e2 = __builtin_amdgcn_exp2f(st[u][2]);
                    float e3 = __builtin_amdgcn_exp2f(st[u][3]);
                    pk[u][ml][0] = pack_bf2(e1, e0);
                    pk[u][ml][1] = pack_bf2(e3, e2);
                }
            }

            // --- lane exchange P^T -> PV B-frags (pure VALU permlane) ---
            bf16x8 pb[2];
            #pragma unroll
            for (int u = 0; u < 2; ++u) {
                uint2v a0 = __builtin_amdgcn_permlane32_swap(pk[u][0][0], pk[u][1][0], false, false);
                uint2v b0 = __builtin_amdgcn_permlane16_swap(a0[0], a0[1], false, false);
                uint2v a1 = __builtin_amdgcn_permlane32_swap(pk[u][0][1], pk[u][1][1], false, false);
                uint2v b1 = __builtin_amdgcn_permlane16_swap(a1[0], a1[1], false, false);
                int4 wv;
                wv.x = (int)b0[0];
                wv.y = (int)b1[0];
                wv.z = (int)b0[1];
                wv.w = (int)b1[1];
                pb[u] = *(bf16x8*)&wv;
            }

            // --- PV: O^T += V^T · P^T  (+ denominator row-sum) ---
            __builtin_amdgcn_s_setprio(1);
            #pragma unroll
            for (int u = 0; u < 2; ++u)
                lsum[u] = __builtin_amdgcn_mfma_f32_16x16x32_bf16(onesf, pb[u], lsum[u], 0, 0, 0);
            #pragma unroll
            for (int jd = 0; jd < 4; ++jd) {
                const int slot = (kc * 4 + q4) ^ lr7;
                bf16x8 vf = *(const bf16x8*)&Vts[cur][(jd * 16 + lr) * 64 + slot * 8];
                #pragma unroll
                for (int u = 0; u < 2; ++u)
                    o[u][jd] = __builtin_amdgcn_mfma_f32_16x16x32_bf16(vf, pb[u], o[u][jd], 0, 0, 0);
            }
            __builtin_amdgcn_s_setprio(0);
        }
        cur ^= 1;
    }

    #pragma unroll
    for (int u = 0; u < 2; ++u) {
        const float inv = __builtin_amdgcn_rcpf(lsum[u][0]);
        const size_t rowO = (size_t)(qrow0 + u * 16 + lr);
        #pragma unroll
        for (int jd = 0; jd < 4; ++jd) {
            ushortx4 v;
            #pragma unroll
            for (int p = 0; p < 4; ++p)
                v[p] = f2bf(o[u][jd][p] * inv);
            *(ushortx4*)&HC[rowO * 1024 + h * 64 + jd * 16 + q4 * 4] = v;
        }
    }
}

// ---------------------------------------------------------------------------
extern "C" void kernel_launch(void* const* d_in, const int* in_sizes, int n_in,
                              void* d_out, int out_size, void* d_ws, size_t ws_size,
                              hipStream_t stream)
{
    const float* x  = (const float*)d_in[0];
    const float* Wq = (const float*)d_in[1];
    const float* Wk = (const float*)d_in[2];
    const float* Wv = (const float*)d_in[3];
    const float* Wo = (const float*)d_in[4];
    float* out = (float*)d_out;

    char* ws = (char*)d_ws;
    unsigned short* XB    = (unsigned short*)(ws);              // 16777216 (aliases HC)
    unsigned short* HC    = (unsigned short*)(ws);
    unsigned short* WQKVT = (unsigned short*)(ws + 16777216);   // 6291456
    unsigned short* WOT   = (unsigned short*)(ws + 23068672);   // 2097152
    unsigned short* QK    = (unsigned short*)(ws + 25165824);   // 33554432
    unsigned short* VT    = (unsigned short*)(ws + 58720256);   // 16777216
    // total ws: 75497472 B (~72 MiB)

    pack_all<<<4608, 256, 0, stream>>>(x, Wq, Wk, Wv, Wo, XB, WQKVT, WOT);
    gemm_qkv8<<<dim3(12, 32), 512, 0, stream>>>(XB, WQKVT, QK, VT);
    attn_flash<<<dim3(64, 16), 256, 0, stream>>>(QK, VT, HC);
    gemm_bt<0, 128><<<dim3(8, 64), 256, 0, stream>>>(HC, WOT, out, nullptr, 8192, 1024, 1024, 1024);
}

// Round 12
// 274.464 us; speedup vs baseline: 1.0350x; 1.0049x over previous
//
#include <hip/hip_runtime.h>

// MultiHeadAttention: B=4, S=2048, D=1024, H=16, dk=dv=64.
// Inputs fp32, output fp32; compute bf16 MFMA.
// R9: attention computes S^T = K·Q^T so P^T exits MFMA in a layout reachable
// from the PV B-operand by a pure lane permutation -- no P LDS round-trip.
// R10: attn VALU diet: builtin exp2, ones-MFMA denominator, v_perm pack.
// R12: ds_bpermute -> permlane32/16_swap: conflicts 8.4M->0, attn 112->83us.
// R16: pack_all LDS-transpose.  R18: QKV XCD swizzle; attn setprio.
// R19: QKV 8-phase REGRESSED (no swizzle -> 14.16M conflicts).
// R20: T2 swizzle -> conflicts 0, but only 96.5->83.7us, MfmaUtil 23.8:
// prefetch was 1 phase deep -- vmcnt(2) at the gate drained loads issued
// ~16 MFMA earlier, exposing ~300cy latency each tile.  (Plus latent t=15
// hole: skipped stages left A1's loads undrained at vmcnt(2).)
// R21: deepen prefetch: ALL 4 halves of tile t+1 issued in phases 0-1
// (B0,B1 @ ph0; A0,A1 @ ph1), gate vmcnt(4) -> youngest needed half is 3
// phases (~48 MFMA) old.  Final tile gates vmcnt(0).  Hazards: ph0 stages
// write Bs[!cur] vs straggler reads As[cur] (disjoint arrays); ph1 stages
// write As[!cur] vs reads As/Bs[cur] (disjoint halves).

typedef __attribute__((ext_vector_type(8))) short bf16x8;   // 8 bf16 = 4 VGPRs
typedef __attribute__((ext_vector_type(4))) float f32x4;
typedef __attribute__((ext_vector_type(4))) unsigned short ushortx4;
typedef __attribute__((ext_vector_type(2))) unsigned int uint2v;

__device__ __forceinline__ unsigned short f2bf(float x) {   // RNE
    unsigned int u = __float_as_uint(x);
    u += 0x7FFFu + ((u >> 16) & 1u);
    return (unsigned short)(u >> 16);
}
// pack two floats as truncated bf16 pair: [hi.bf16 : lo.bf16] -- v_perm_b32
__device__ __forceinline__ unsigned int pack_bf2(float hi, float lo) {
    return __builtin_amdgcn_perm(__float_as_uint(hi), __float_as_uint(lo), 0x07060302u);
}

// async 16B global -> LDS (lds dest wave-uniform; HW adds lane*16)
__device__ __forceinline__ void gload_lds16(const unsigned short* g, unsigned short* lds) {
    __builtin_amdgcn_global_load_lds(
        (const __attribute__((address_space(1))) unsigned int*)g,
        (__attribute__((address_space(3))) unsigned int*)lds,
        16, 0, 0);
}

// ---------------------------------------------------------------------------
// One merged pack kernel. Sections by blockIdx.x:
//  [0,4096):      XB  = bf16(x)                       (coalesced)
//  [4096,4480):   WQKVT[n][d]  via LDS-transposed tiles (Wq scaled)
//  [4480,4608):   WOT[n][k] = Wo[k][n] via LDS-transposed tiles
__global__ __launch_bounds__(256) void pack_all(
    const float* __restrict__ x,
    const float* __restrict__ Wq,
    const float* __restrict__ Wk,
    const float* __restrict__ Wv,
    const float* __restrict__ Wo,
    unsigned short* __restrict__ XB,
    unsigned short* __restrict__ WQKVT,
    unsigned short* __restrict__ WOT)
{
    const int bid = blockIdx.x;
    const int tid = threadIdx.x;
    if (bid < 4096) {
        bf16x8 v;
        size_t base = ((size_t)bid * 256 + tid) * 8;
        float4 f0 = *(const float4*)&x[base];
        float4 f1 = *(const float4*)&x[base + 4];
        v[0] = f2bf(f0.x); v[1] = f2bf(f0.y); v[2] = f2bf(f0.z); v[3] = f2bf(f0.w);
        v[4] = f2bf(f1.x); v[5] = f2bf(f1.y); v[6] = f2bf(f1.z); v[7] = f2bf(f1.w);
        *(bf16x8*)&XB[base] = v;
        return;
    }

    __shared__ float lds[64 * 129];
    const float* src;
    size_t outbase;
    float scale = 1.0f;
    int instride;
    unsigned short* outp;
    if (bid < 4480) {
        const int widx = bid - 4096;
        const int part = widx >> 7;           // 0..2 (q,k,v)
        const int rem  = widx & 127;
        const int h    = rem >> 3;            // 0..15
        const int chunk = rem & 7;            // d-chunk of 128
        const float* W = (part == 0) ? Wq : ((part == 1) ? Wk : Wv);
        src = W + h * 65536 + chunk * 8192;   // [128 d][64 kk], row stride 64
        instride = 64;
        outbase = ((size_t)(part * 1024 + h * 64)) * 1024 + chunk * 128;
        if (part == 0) scale = 0.125f * 1.44269504088896f;
        outp = WQKVT;
    } else {
        const int oidx = bid - 4480;
        const int kc = oidx >> 4;             // k-chunk of 128 (0..7)
        const int nc = oidx & 15;             // n-chunk of 64  (0..15)
        src = Wo + (size_t)kc * 128 * 1024 + nc * 64;   // [128 k][64 n], stride 1024
        instride = 1024;
        outbase = (size_t)(nc * 64) * 1024 + kc * 128;
        outp = WOT;
    }

    // read phase: [128 r][64 c] tile -> lds[c*129 + r]
    const int r0 = tid >> 4;                  // 0..15
    const int c4 = (tid & 15) * 4;            // 0,4,..,60
    #pragma unroll
    for (int cc = 0; cc < 8; ++cc) {
        const int r = cc * 16 + r0;
        float4 f = *(const float4*)&src[(size_t)r * instride + c4];
        lds[(c4 + 0) * 129 + r] = f.x * scale;
        lds[(c4 + 1) * 129 + r] = f.y * scale;
        lds[(c4 + 2) * 129 + r] = f.z * scale;
        lds[(c4 + 3) * 129 + r] = f.w * scale;
    }
    __syncthreads();

    // write phase: 64 out-rows (c), 128 bf16 each
    const int c = tid >> 2;                   // 0..63
    const int s = tid & 3;                    // 0..3
    #pragma unroll
    for (int j = 0; j < 4; ++j) {
        bf16x8 v;
        #pragma unroll
        for (int e = 0; e < 8; ++e)
            v[e] = f2bf(lds[c * 129 + s * 32 + j * 8 + e]);
        *(bf16x8*)&outp[outbase + (size_t)c * 1024 + s * 32 + j * 8] = v;
    }
}

// ---------------------------------------------------------------------------
// 2-phase GEMM (kept for the out projection): C = A @ Bt^T, fp32 C.
template<int CMODE, int BN>
__global__ __launch_bounds__(256) void gemm_bt(
    const unsigned short* __restrict__ A,
    const unsigned short* __restrict__ Bt,
    void* __restrict__ Cv,
    unsigned short* __restrict__ VT,
    int M, int N, int K, int ldc)
{
    __shared__ __align__(16) unsigned short As[2][128 * 32];
    __shared__ __align__(16) unsigned short Bs[2][BN * 32];

    // T1 swizzle (bijective: grid size divisible by 8)
    const int flat = blockIdx.y * gridDim.x + blockIdx.x;
    const int cpx  = (gridDim.x * gridDim.y) >> 3;
    const int swz  = (flat & 7) * cpx + (flat >> 3);
    const int m0 = (swz / gridDim.x) * 128;
    const int n0 = (swz % gridDim.x) * BN;

    const int tid  = threadIdx.x;
    const int w    = tid >> 6, lane = tid & 63;
    const int q4   = lane >> 4, lr  = lane & 15;
    constexpr int MI = (BN == 128) ? 4 : 2;
    const int rowBase = (BN == 128) ? (w >> 1) * 64 : w * 32;
    const int colBase = (BN == 128) ? (w & 1) * 64 : 0;

    const int ch   = tid & 3;
    const int row0 = tid >> 2;
    const int ldsOff = w * 512;   // halfwords; HW adds lane*16B

    const unsigned short* aP0 = &A [(size_t)(m0 + row0)      * K + ch * 8];
    const unsigned short* aP1 = &A [(size_t)(m0 + row0 + 64) * K + ch * 8];
    const unsigned short* bP0 = &Bt[(size_t)(n0 + row0)      * K + ch * 8];
    const unsigned short* bP1 = (BN == 128)
        ? &Bt[(size_t)(n0 + row0 + 64) * K + ch * 8] : nullptr;

    auto dma = [&](int buf, int k0) {
        gload_lds16(aP0 + k0, &As[buf][ldsOff]);
        gload_lds16(aP1 + k0, &As[buf][2048 + ldsOff]);
        gload_lds16(bP0 + k0, &Bs[buf][ldsOff]);
        if (BN == 128)
            gload_lds16(bP1 + k0, &Bs[buf][2048 + ldsOff]);
    };

    f32x4 acc[MI][4] = {};
    dma(0, 0);
    int cur = 0;

    for (int k0 = 0; k0 < K; k0 += 32) {
        __syncthreads();                          // drains DMA(k0) -> buf[cur] ready
        if (k0 + 32 < K) dma(cur ^ 1, k0 + 32);   // in flight during compute

        bf16x8 af[MI], bfv[4];
        #pragma unroll
        for (int i = 0; i < MI; ++i)
            af[i] = *(const bf16x8*)&As[cur][(rowBase + i * 16 + lr) * 32 + q4 * 8];
        #pragma unroll
        for (int j = 0; j < 4; ++j)
            bfv[j] = *(const bf16x8*)&Bs[cur][(colBase + j * 16 + lr) * 32 + q4 * 8];
        #pragma unroll
        for (int i = 0; i < MI; ++i)
            #pragma unroll
            for (int j = 0; j < 4; ++j)
                acc[i][j] = __builtin_amdgcn_mfma_f32_16x16x32_bf16(af[i], bfv[j], acc[i][j], 0, 0, 0);
        cur ^= 1;
    }

    #pragma unroll
    for (int i = 0; i < MI; ++i) {
        const int row = m0 + rowBase + i * 16 + q4 * 4;
        #pragma unroll
        for (int j = 0; j < 4; ++j) {
            const int col = n0 + colBase + j * 16 + lr;
            if (CMODE == 0) {
                float* C = (float*)Cv;
                #pragma unroll
                for (int p = 0; p < 4; ++p)
                    C[(size_t)(row + p) * ldc + col] = acc[i][j][p];
            } else {
                if (col < 2048) {
                    unsigned short* C = (unsigned short*)Cv;
                    #pragma unroll
                    for (int p = 0; p < 4; ++p)
                        C[(size_t)(row + p) * 2048 + col] = f2bf(acc[i][j][p]);
                } else {
                    const int c2 = col - 2048;
                    const int hh = c2 >> 6, dd = c2 & 63;
                    const int bb = row >> 11, ss = row & 2047;
                    ushortx4 v;
                    #pragma unroll
                    for (int p = 0; p < 4; ++p) v[p] = f2bf(acc[i][j][p]);
                    *(ushortx4*)&VT[((size_t)(bb * 16 + hh) * 64 + dd) * 2048 + ss] = v;
                }
            }
        }
    }
}

// ---------------------------------------------------------------------------
// R21 QKV GEMM: 256x256 tile, BK=64, 512 threads (8 waves 2Mx4N, 128x64 each),
// double-buffered 128KB LDS, 4 phases/tile.  T2 XOR swizzle (0 conflicts).
// Prefetch: all 4 halves of tile t+1 issued in phases 0-1 of tile t
// (B0,B1 @ ph0, A0,A1 @ ph1); gate vmcnt(4) -> tile t's youngest half is
// 3 phases old.  Final tile gates vmcnt(0).
__global__ __launch_bounds__(512, 2) void gemm_qkv8(
    const unsigned short* __restrict__ A,    // XB [8192][1024]
    const unsigned short* __restrict__ Bt,   // WQKVT [3072][1024]
    unsigned short* __restrict__ QK,         // [8192][2048]
    unsigned short* __restrict__ VT)
{
    constexpr int K = 1024;
    __shared__ __align__(16) unsigned short As[32768];   // 2 buf x 2 half x 8192
    __shared__ __align__(16) unsigned short Bs[32768];

    // T1 XCD-chunked swizzle: 384 blocks, 48 per XCD
    const int flat = blockIdx.y * 12 + blockIdx.x;
    const int swz  = (flat & 7) * 48 + (flat >> 3);
    const int m0 = (swz / 12) * 256;
    const int n0 = (swz % 12) * 256;

    const int tid  = threadIdx.x;
    const int w    = tid >> 6, lane = tid & 63;
    const int q4   = lane >> 4, lr  = lane & 15;
    const int lr7  = lr & 7;
    const int wr   = w >> 3, wc = w & 3;      // (wr = w>>2 below; see wave map)
    const int wrr  = w >> 2;                  // wave rows: wrr*128
    const unsigned short* pA;
    const unsigned short* pB;

    // pre-swizzled global source (T2 via m173: dest linear, source permuted)
    const int srow = tid >> 3;                // 0..63 (row within half, mod 64)
    const int gch  = (tid & 7) ^ (srow & 7);  // XOR key invariant: rows step by 64/128
    pA = A  + (size_t)(m0 + srow) * K + gch * 8;
    pB = Bt + (size_t)(n0 + srow) * K + gch * 8;
    const int woff = w * 512;                 // halfwords; HW adds lane*16B
    (void)wr;

    // half h (0..63): tile t=h>>2, kind h&3: 0=B0 1=B1 2=A0 3=A1
    auto stage = [&](int h) {
        if (h >= 64) return;
        const int t = h >> 2, kind = h & 3, buf = t & 1;
        if (kind >= 2) {
            const int i = kind - 2;
            const unsigned short* s = pA + (size_t)(i * 128) * K + t * 64;
            unsigned short* d = &As[buf * 16384 + i * 8192 + woff];
            gload_lds16(s, d);
            gload_lds16(s + (size_t)64 * K, d + 4096);
        } else {
            const unsigned short* s = pB + (size_t)(kind * 128) * K + t * 64;
            unsigned short* d = &Bs[buf * 16384 + kind * 8192 + woff];
            gload_lds16(s, d);
            gload_lds16(s + (size_t)64 * K, d + 4096);
        }
    };

    // prologue: tile 0's 4 halves (8 loads/thread, in flight)
    stage(0); stage(1); stage(2); stage(3);

    f32x4 acc[8][4] = {};

    for (int t = 0; t < 16; ++t) {
        const int buf = t & 1;
        const unsigned short* Ab = &As[buf * 16384 + wrr * 8192];
        const unsigned short* Bb = &Bs[buf * 16384 + (wc >> 1) * 8192];
        const int brow = (wc & 1) * 64;
        bf16x8 bf[4][2];

        // ---- phase 0: stage B0,B1 of t+1; gate tile t; B frags + m-group 0 ----
        stage(4 * t + 4);                      // B0 of t+1 (vs straggler A reads: disjoint)
        stage(4 * t + 5);                      // B1 of t+1
        if (t == 15) asm volatile("s_waitcnt vmcnt(0)" ::: "memory");
        else         asm volatile("s_waitcnt vmcnt(4)" ::: "memory");   // tile t landed
        __builtin_amdgcn_s_barrier();
        #pragma unroll
        for (int n = 0; n < 4; ++n)
            #pragma unroll
            for (int ks = 0; ks < 2; ++ks) {
                const int slot = (ks * 4 + q4) ^ lr7;
                bf[n][ks] = *(const bf16x8*)&Bb[(brow + n * 16 + lr) * 64 + slot * 8];
            }
        {
            bf16x8 af[2][2];
            #pragma unroll
            for (int mm = 0; mm < 2; ++mm)
                #pragma unroll
                for (int ks = 0; ks < 2; ++ks) {
                    const int slot = (ks * 4 + q4) ^ lr7;
                    af[mm][ks] = *(const bf16x8*)&Ab[(mm * 16 + lr) * 64 + slot * 8];
                }
            __builtin_amdgcn_s_setprio(1);
            #pragma unroll
            for (int mm = 0; mm < 2; ++mm)
                #pragma unroll
                for (int n = 0; n < 4; ++n)
                    #pragma unroll
                    for (int ks = 0; ks < 2; ++ks)
                        acc[mm][n] = __builtin_amdgcn_mfma_f32_16x16x32_bf16(af[mm][ks], bf[n][ks], acc[mm][n], 0, 0, 0);
            __builtin_amdgcn_s_setprio(0);
        }

        // ---- phases 1..3: m-groups 1..3 (A halves of t+1 staged at phase 1) ----
        #pragma unroll
        for (int p = 1; p < 4; ++p) {
            if (p == 1) { stage(4 * t + 6); stage(4 * t + 7); }   // A0,A1 of t+1
            __builtin_amdgcn_s_barrier();
            bf16x8 af[2][2];
            #pragma unroll
            for (int mm = 0; mm < 2; ++mm)
                #pragma unroll
                for (int ks = 0; ks < 2; ++ks) {
                    const int slot = (ks * 4 + q4) ^ lr7;
                    af[mm][ks] = *(const bf16x8*)&Ab[(p * 32 + mm * 16 + lr) * 64 + slot * 8];
                }
            __builtin_amdgcn_s_setprio(1);
            #pragma unroll
            for (int mm = 0; mm < 2; ++mm)
                #pragma unroll
                for (int n = 0; n < 4; ++n)
                    #pragma unroll
                    for (int ks = 0; ks < 2; ++ks)
                        acc[p * 2 + mm][n] = __builtin_amdgcn_mfma_f32_16x16x32_bf16(af[mm][ks], bf[n][ks], acc[p * 2 + mm][n], 0, 0, 0);
            __builtin_amdgcn_s_setprio(0);
        }
    }

    // epilogue (same store forms as R13)
    #pragma unroll
    for (int m = 0; m < 8; ++m) {
        const int row = m0 + wrr * 128 + m * 16 + q4 * 4;
        #pragma unroll
        for (int n = 0; n < 4; ++n) {
            const int col = n0 + wc * 64 + n * 16 + lr;
            if (col < 2048) {
                #pragma unroll
                for (int p = 0; p < 4; ++p)
                    QK[(size_t)(row + p) * 2048 + col] = f2bf(acc[m][n][p]);
            } else {
                const int c2 = col - 2048;
                const int hh = c2 >> 6, dd = c2 & 63;
                const int bb = row >> 11, ss = row & 2047;
                ushortx4 v;
                #pragma unroll
                for (int p = 0; p < 4; ++p) v[p] = f2bf(acc[m][n][p]);
                *(ushortx4*)&VT[((size_t)(bb * 16 + hh) * 64 + dd) * 2048 + ss] = v;
            }
        }
    }
}

// ---------------------------------------------------------------------------
// Flash attention, transposed-P scheme (R18 config, unchanged).
__global__ __launch_bounds__(256, 4) void attn_flash(
    const unsigned short* __restrict__ QK,
    const unsigned short* __restrict__ VT,
    unsigned short* __restrict__ HC)        // [8192][1024] bf16
{
    const int bh  = blockIdx.x;   // b*16+h  (fastest dim -> XCD-pinned K/V reuse)
    const int qb  = blockIdx.y;   // 0..15
    const int b   = bh >> 4, h = bh & 15;
    const int tid = threadIdx.x;
    const int w   = tid >> 6, lane = tid & 63;
    const int q4  = lane >> 4, lr  = lane & 15;

    __shared__ __align__(16) unsigned short Ks [2][64 * 64];   // [key][dk] swizzled
    __shared__ __align__(16) unsigned short Vts[2][64 * 64];   // [d][key]  swizzled

    // DMA mapping: round R covers rows R*32+(tid>>3), chunk slot tid&7.
    const int drow   = tid >> 3;                       // 0..31
    const int gchunk = (tid & 7) ^ (drow & 7);         // global chunk for slot tid&7
    const unsigned short* Kg = QK + (size_t)(b * 2048) * 2048 + 1024 + h * 64;
    const unsigned short* Vg = VT + (size_t)bh * 64 * 2048;
    // running global pointers (advance per 64-key tile)
    const unsigned short* kP0 = Kg + (size_t)(drow)      * 2048 + gchunk * 8;
    const unsigned short* kP1 = Kg + (size_t)(drow + 32) * 2048 + gchunk * 8;
    const unsigned short* vP0 = Vg + (size_t)(drow)      * 2048 + gchunk * 8;
    const unsigned short* vP1 = Vg + (size_t)(drow + 32) * 2048 + gchunk * 8;
    const int ldsOff = w * 512;                        // halfwords; +lane*8 by HW

    auto dma = [&](int buf, int t) {
        gload_lds16(kP0 + (size_t)t * 131072, &Ks [buf][ldsOff]);
        gload_lds16(kP1 + (size_t)t * 131072, &Ks [buf][2048 + ldsOff]);
        gload_lds16(vP0 + t * 64,             &Vts[buf][ldsOff]);
        gload_lds16(vP1 + t * 64,             &Vts[buf][2048 + ldsOff]);
    };

    dma(0, 0);

    const int qrow0 = b * 2048 + qb * 128 + w * 32;
    bf16x8 qf[2][2];   // B-frag of Q^T == A-frag of Q: Q[q=lr][dk=c*32+q4*8+j]
    #pragma unroll
    for (int u = 0; u < 2; ++u)
        #pragma unroll
        for (int c = 0; c < 2; ++c)
            qf[u][c] = *(const bf16x8*)&QK[(size_t)(qrow0 + u * 16 + lr) * 2048
                                           + h * 64 + c * 32 + q4 * 8];

    const int lr7 = lr & 7;

    // ones A-fragment (bf16 1.0) for denominator row-sum MFMA
    const short oneb = (short)0x3F80;
    const bf16x8 onesf = { oneb, oneb, oneb, oneb, oneb, oneb, oneb, oneb };

    f32x4 o[2][4] = {};      // O^T[d=jd*16+q4*4+p][q=u*16+lr]
    f32x4 lsum[2] = {};      // denominator: all rows equal = sum_k P^T[k][q=lr]
    int cur = 0;

    for (int t = 0; t < 32; ++t) {
        __syncthreads();                       // drains DMA(t) -> buf[cur] ready
        if (t + 1 < 32) dma(cur ^ 1, t + 1);   // in flight during compute

        #pragma unroll
        for (int kc = 0; kc < 2; ++kc) {
            // --- S^T for this 32-key chunk (2 mt subtiles) ---
            unsigned int pk[2][2][2];          // packed P^T words [u][ml][i]
            #pragma unroll
            for (int ml = 0; ml < 2; ++ml) {
                const int mt = kc * 2 + ml;
                f32x4 st[2] = {};
                __builtin_amdgcn_s_setprio(1);
                #pragma unroll
                for (int c = 0; c < 2; ++c) {
                    const int slot = (c * 4 + q4) ^ lr7;
                    bf16x8 kf = *(const bf16x8*)&Ks[cur][(mt * 16 + lr) * 64 + slot * 8];
                    #pragma unroll
                    for (int u = 0; u < 2; ++u)
                        st[u] = __builtin_amdgcn_mfma_f32_16x16x32_bf16(kf, qf[u][c], st[u], 0, 0, 0);
                }
                __builtin_amdgcn_s_setprio(0);
                #pragma unroll
                for (int u = 0; u < 2; ++u) {
                    float e0 = __builtin_amdgcn_exp2f(st[u][0]);
                    float e1 = __builtin_amdgcn_exp2f(st[u][1]);
                    float e2 = __builtin_amdgcn_exp2f(st[u][2]);
                    float e3 = __builtin_amdgcn_exp2f(st[u][3]);
                    pk[u][ml][0] = pack_bf2(e1, e0);
                    pk[u][ml][1] = pack_bf2(e3, e2);
                }
            }

            // --- lane exchange P^T -> PV B-frags (pure VALU permlane) ---
            bf16x8 pb[2];
            #pragma unroll
            for (int u = 0; u < 2; ++u) {
                uint2v a0 = __builtin_amdgcn_permlane32_swap(pk[u][0][0], pk[u][1][0], false, false);
                uint2v b0 = __builtin_amdgcn_permlane16_swap(a0[0], a0[1], false, false);
                uint2v a1 = __builtin_amdgcn_permlane32_swap(pk[u][0][1], pk[u][1][1], false, false);
                uint2v b1 = __builtin_amdgcn_permlane16_swap(a1[0], a1[1], false, false);
                int4 wv;
                wv.x = (int)b0[0];
                wv.y = (int)b1[0];
                wv.z = (int)b0[1];
                wv.w = (int)b1[1];
                pb[u] = *(bf16x8*)&wv;
            }

            // --- PV: O^T += V^T · P^T  (+ denominator row-sum) ---
            __builtin_amdgcn_s_setprio(1);
            #pragma unroll
            for (int u = 0; u < 2; ++u)
                lsum[u] = __builtin_amdgcn_mfma_f32_16x16x32_bf16(onesf, pb[u], lsum[u], 0, 0, 0);
            #pragma unroll
            for (int jd = 0; jd < 4; ++jd) {
                const int slot = (kc * 4 + q4) ^ lr7;
                bf16x8 vf = *(const bf16x8*)&Vts[cur][(jd * 16 + lr) * 64 + slot * 8];
                #pragma unroll
                for (int u = 0; u < 2; ++u)
                    o[u][jd] = __builtin_amdgcn_mfma_f32_16x16x32_bf16(vf, pb[u], o[u][jd], 0, 0, 0);
            }
            __builtin_amdgcn_s_setprio(0);
        }
        cur ^= 1;
    }

    #pragma unroll
    for (int u = 0; u < 2; ++u) {
        const float inv = __builtin_amdgcn_rcpf(lsum[u][0]);
        const size_t rowO = (size_t)(qrow0 + u * 16 + lr);
        #pragma unroll
        for (int jd = 0; jd < 4; ++jd) {
            ushortx4 v;
            #pragma unroll
            for (int p = 0; p < 4; ++p)
                v[p] = f2bf(o[u][jd][p] * inv);
            *(ushortx4*)&HC[rowO * 1024 + h * 64 + jd * 16 + q4 * 4] = v;
        }
    }
}

// ---------------------------------------------------------------------------
extern "C" void kernel_launch(void* const* d_in, const int* in_sizes, int n_in,
                              void* d_out, int out_size, void* d_ws, size_t ws_size,
                              hipStream_t stream)
{
    const float* x  = (const float*)d_in[0];
    const float* Wq = (const float*)d_in[1];
    const float* Wk = (const float*)d_in[2];
    const float* Wv = (const float*)d_in[3];
    const float* Wo = (const float*)d_in[4];
    float* out = (float*)d_out;

    char* ws = (char*)d_ws;
    unsigned short* XB    = (unsigned short*)(ws);              // 16777216 (aliases HC)
    unsigned short* HC    = (unsigned short*)(ws);
    unsigned short* WQKVT = (unsigned short*)(ws + 16777216);   // 6291456
    unsigned short* WOT   = (unsigned short*)(ws + 23068672);   // 2097152
    unsigned short* QK    = (unsigned short*)(ws + 25165824);   // 33554432
    unsigned short* VT    = (unsigned short*)(ws + 58720256);   // 16777216
    // total ws: 75497472 B (~72 MiB)

    pack_all<<<4608, 256, 0, stream>>>(x, Wq, Wk, Wv, Wo, XB, WQKVT, WOT);
    gemm_qkv8<<<dim3(12, 32), 512, 0, stream>>>(XB, WQKVT, QK, VT);
    attn_flash<<<dim3(64, 16), 256, 0, stream>>>(QK, VT, HC);
    gemm_bt<0, 128><<<dim3(8, 64), 256, 0, stream>>>(HC, WOT, out, nullptr, 8192, 1024, 1024, 1024);
}

// Round 13
// 264.647 us; speedup vs baseline: 1.0734x; 1.0371x over previous
//
#include <hip/hip_runtime.h>

// MultiHeadAttention: B=4, S=2048, D=1024, H=16, dk=dv=64.
// Inputs fp32, output fp32; compute bf16 MFMA.
// R9: attention computes S^T = K·Q^T so P^T exits MFMA in a layout reachable
// from the PV B-operand by a pure lane permutation -- no P LDS round-trip.
// R10: attn VALU diet: builtin exp2, ones-MFMA denominator, v_perm pack.
// R12: ds_bpermute -> permlane32/16_swap: conflicts 8.4M->0, attn 112->83us.
// R13: gemm_bt double-buffered, 1 barrier/K-step.
// R16: pack_all LDS-transpose (-19us).  R17: out tile shape NEUTRAL.
// R18: QKV XCD-chunked swizzle (-3.5us); attn setprio (-1.7us).  BEST: 260.9.
// R19-R21: QKV 8-phase branch (T3+T4) abandoned: R19 96.5us (no T2, 14.2M
// conflicts), R20 +T2 83.7us (conflicts 0 but 1 block/CU + per-phase B-frag
// re-read leaves too little overlap), R21 deeper prefetch 101us (latency at
// the gate was NOT the residual).  Pre-commit tripped -> revert to R18 2ph.
// R22: pure restoration of the R18-measured configuration.

typedef __attribute__((ext_vector_type(8))) short bf16x8;   // 8 bf16 = 4 VGPRs
typedef __attribute__((ext_vector_type(4))) float f32x4;
typedef __attribute__((ext_vector_type(4))) unsigned short ushortx4;
typedef __attribute__((ext_vector_type(2))) unsigned int uint2v;

__device__ __forceinline__ unsigned short f2bf(float x) {   // RNE
    unsigned int u = __float_as_uint(x);
    u += 0x7FFFu + ((u >> 16) & 1u);
    return (unsigned short)(u >> 16);
}
// pack two floats as truncated bf16 pair: [hi.bf16 : lo.bf16] -- v_perm_b32
__device__ __forceinline__ unsigned int pack_bf2(float hi, float lo) {
    return __builtin_amdgcn_perm(__float_as_uint(hi), __float_as_uint(lo), 0x07060302u);
}

// async 16B global -> LDS (lds dest wave-uniform; HW adds lane*16)
__device__ __forceinline__ void gload_lds16(const unsigned short* g, unsigned short* lds) {
    __builtin_amdgcn_global_load_lds(
        (const __attribute__((address_space(1))) unsigned int*)g,
        (__attribute__((address_space(3))) unsigned int*)lds,
        16, 0, 0);
}

// ---------------------------------------------------------------------------
// One merged pack kernel. Sections by blockIdx.x:
//  [0,4096):      XB  = bf16(x)                       (coalesced)
//  [4096,4480):   WQKVT[n][d]  via LDS-transposed tiles (Wq scaled)
//  [4480,4608):   WOT[n][k] = Wo[k][n] via LDS-transposed tiles
__global__ __launch_bounds__(256) void pack_all(
    const float* __restrict__ x,
    const float* __restrict__ Wq,
    const float* __restrict__ Wk,
    const float* __restrict__ Wv,
    const float* __restrict__ Wo,
    unsigned short* __restrict__ XB,
    unsigned short* __restrict__ WQKVT,
    unsigned short* __restrict__ WOT)
{
    const int bid = blockIdx.x;
    const int tid = threadIdx.x;
    if (bid < 4096) {
        bf16x8 v;
        size_t base = ((size_t)bid * 256 + tid) * 8;
        float4 f0 = *(const float4*)&x[base];
        float4 f1 = *(const float4*)&x[base + 4];
        v[0] = f2bf(f0.x); v[1] = f2bf(f0.y); v[2] = f2bf(f0.z); v[3] = f2bf(f0.w);
        v[4] = f2bf(f1.x); v[5] = f2bf(f1.y); v[6] = f2bf(f1.z); v[7] = f2bf(f1.w);
        *(bf16x8*)&XB[base] = v;
        return;
    }

    __shared__ float lds[64 * 129];
    const float* src;
    size_t outbase;
    float scale = 1.0f;
    int instride;
    unsigned short* outp;
    if (bid < 4480) {
        const int widx = bid - 4096;
        const int part = widx >> 7;           // 0..2 (q,k,v)
        const int rem  = widx & 127;
        const int h    = rem >> 3;            // 0..15
        const int chunk = rem & 7;            // d-chunk of 128
        const float* W = (part == 0) ? Wq : ((part == 1) ? Wk : Wv);
        src = W + h * 65536 + chunk * 8192;   // [128 d][64 kk], row stride 64
        instride = 64;
        outbase = ((size_t)(part * 1024 + h * 64)) * 1024 + chunk * 128;
        if (part == 0) scale = 0.125f * 1.44269504088896f;
        outp = WQKVT;
    } else {
        const int oidx = bid - 4480;
        const int kc = oidx >> 4;             // k-chunk of 128 (0..7)
        const int nc = oidx & 15;             // n-chunk of 64  (0..15)
        src = Wo + (size_t)kc * 128 * 1024 + nc * 64;   // [128 k][64 n], stride 1024
        instride = 1024;
        outbase = (size_t)(nc * 64) * 1024 + kc * 128;
        outp = WOT;
    }

    // read phase: [128 r][64 c] tile -> lds[c*129 + r]
    const int r0 = tid >> 4;                  // 0..15
    const int c4 = (tid & 15) * 4;            // 0,4,..,60
    #pragma unroll
    for (int cc = 0; cc < 8; ++cc) {
        const int r = cc * 16 + r0;
        float4 f = *(const float4*)&src[(size_t)r * instride + c4];
        lds[(c4 + 0) * 129 + r] = f.x * scale;
        lds[(c4 + 1) * 129 + r] = f.y * scale;
        lds[(c4 + 2) * 129 + r] = f.z * scale;
        lds[(c4 + 3) * 129 + r] = f.w * scale;
    }
    __syncthreads();

    // write phase: 64 out-rows (c), 128 bf16 each
    const int c = tid >> 2;                   // 0..63
    const int s = tid & 3;                    // 0..3
    #pragma unroll
    for (int j = 0; j < 4; ++j) {
        bf16x8 v;
        #pragma unroll
        for (int e = 0; e < 8; ++e)
            v[e] = f2bf(lds[c * 129 + s * 32 + j * 8 + e]);
        *(bf16x8*)&outp[outbase + (size_t)c * 1024 + s * 32 + j * 8] = v;
    }
}

// ---------------------------------------------------------------------------
// C = A[M][K] @ Bt[N][K]^T, A/Bt bf16 row-major, global_load_lds staging into
// double-buffered LDS, 1 barrier per K-step (DMA t+1 in flight across compute t).
// CMODE 0: C fp32 ldc.  CMODE 1: QKV split (QK bf16 / VT transposed).
// XCD-chunked block swizzle: flat ids remapped so XCD k owns a contiguous
// chunk -> A slice L2-resident.  nwg % 8 == 0.
template<int CMODE, int BN>
__global__ __launch_bounds__(256) void gemm_bt(
    const unsigned short* __restrict__ A,
    const unsigned short* __restrict__ Bt,
    void* __restrict__ Cv,
    unsigned short* __restrict__ VT,
    int M, int N, int K, int ldc)
{
    __shared__ __align__(16) unsigned short As[2][128 * 32];
    __shared__ __align__(16) unsigned short Bs[2][BN * 32];

    // T1 swizzle (bijective: grid size divisible by 8)
    const int flat = blockIdx.y * gridDim.x + blockIdx.x;
    const int cpx  = (gridDim.x * gridDim.y) >> 3;
    const int swz  = (flat & 7) * cpx + (flat >> 3);
    const int m0 = (swz / gridDim.x) * 128;
    const int n0 = (swz % gridDim.x) * BN;

    const int tid  = threadIdx.x;
    const int w    = tid >> 6, lane = tid & 63;
    const int q4   = lane >> 4, lr  = lane & 15;
    constexpr int MI = (BN == 128) ? 4 : 2;
    const int rowBase = (BN == 128) ? (w >> 1) * 64 : w * 32;
    const int colBase = (BN == 128) ? (w & 1) * 64 : 0;

    const int ch   = tid & 3;
    const int row0 = tid >> 2;
    const int ldsOff = w * 512;   // halfwords; HW adds lane*16B

    const unsigned short* aP0 = &A [(size_t)(m0 + row0)      * K + ch * 8];
    const unsigned short* aP1 = &A [(size_t)(m0 + row0 + 64) * K + ch * 8];
    const unsigned short* bP0 = &Bt[(size_t)(n0 + row0)      * K + ch * 8];
    const unsigned short* bP1 = (BN == 128)
        ? &Bt[(size_t)(n0 + row0 + 64) * K + ch * 8] : nullptr;

    auto dma = [&](int buf, int k0) {
        gload_lds16(aP0 + k0, &As[buf][ldsOff]);
        gload_lds16(aP1 + k0, &As[buf][2048 + ldsOff]);
        gload_lds16(bP0 + k0, &Bs[buf][ldsOff]);
        if (BN == 128)
            gload_lds16(bP1 + k0, &Bs[buf][2048 + ldsOff]);
    };

    f32x4 acc[MI][4] = {};
    dma(0, 0);
    int cur = 0;

    for (int k0 = 0; k0 < K; k0 += 32) {
        __syncthreads();                          // drains DMA(k0) -> buf[cur] ready
        if (k0 + 32 < K) dma(cur ^ 1, k0 + 32);   // in flight during compute

        bf16x8 af[MI], bfv[4];
        #pragma unroll
        for (int i = 0; i < MI; ++i)
            af[i] = *(const bf16x8*)&As[cur][(rowBase + i * 16 + lr) * 32 + q4 * 8];
        #pragma unroll
        for (int j = 0; j < 4; ++j)
            bfv[j] = *(const bf16x8*)&Bs[cur][(colBase + j * 16 + lr) * 32 + q4 * 8];
        #pragma unroll
        for (int i = 0; i < MI; ++i)
            #pragma unroll
            for (int j = 0; j < 4; ++j)
                acc[i][j] = __builtin_amdgcn_mfma_f32_16x16x32_bf16(af[i], bfv[j], acc[i][j], 0, 0, 0);
        cur ^= 1;
    }

    #pragma unroll
    for (int i = 0; i < MI; ++i) {
        const int row = m0 + rowBase + i * 16 + q4 * 4;
        #pragma unroll
        for (int j = 0; j < 4; ++j) {
            const int col = n0 + colBase + j * 16 + lr;
            if (CMODE == 0) {
                float* C = (float*)Cv;
                #pragma unroll
                for (int p = 0; p < 4; ++p)
                    C[(size_t)(row + p) * ldc + col] = acc[i][j][p];
            } else {
                if (col < 2048) {
                    unsigned short* C = (unsigned short*)Cv;
                    #pragma unroll
                    for (int p = 0; p < 4; ++p)
                        C[(size_t)(row + p) * 2048 + col] = f2bf(acc[i][j][p]);
                } else {
                    const int c2 = col - 2048;
                    const int hh = c2 >> 6, dd = c2 & 63;
                    const int bb = row >> 11, ss = row & 2047;
                    ushortx4 v;
                    #pragma unroll
                    for (int p = 0; p < 4; ++p) v[p] = f2bf(acc[i][j][p]);
                    *(ushortx4*)&VT[((size_t)(bb * 16 + hh) * 64 + dd) * 2048 + ss] = v;
                }
            }
        }
    }
}

// ---------------------------------------------------------------------------
// Flash attention, transposed-P scheme (R18 config).  QK[8192][2048] bf16
// (Q|K), VT[(b*16+h)*64+d][2048] bf16.  WG = (bh, 128-q block); wave w: 32 q
// as 2 subtiles u.  64-key tiles, K/V in XOR-swizzled stride-64 double
// buffers filled by global_load_lds; S^T = K·Q^T; P^T moved to PV B-frags via
// permlane32_swap + permlane16_swap (pure VALU, no LDS); O^T = V^T·P^T.
// Softmax denominator accumulated by a ones-A-frag MFMA.  setprio around
// MFMA clusters (T5).
__global__ __launch_bounds__(256, 4) void attn_flash(
    const unsigned short* __restrict__ QK,
    const unsigned short* __restrict__ VT,
    unsigned short* __restrict__ HC)        // [8192][1024] bf16
{
    const int bh  = blockIdx.x;   // b*16+h  (fastest dim -> XCD-pinned K/V reuse)
    const int qb  = blockIdx.y;   // 0..15
    const int b   = bh >> 4, h = bh & 15;
    const int tid = threadIdx.x;
    const int w   = tid >> 6, lane = tid & 63;
    const int q4  = lane >> 4, lr  = lane & 15;

    __shared__ __align__(16) unsigned short Ks [2][64 * 64];   // [key][dk] swizzled
    __shared__ __align__(16) unsigned short Vts[2][64 * 64];   // [d][key]  swizzled

    // DMA mapping: round R covers rows R*32+(tid>>3), chunk slot tid&7.
    const int drow   = tid >> 3;                       // 0..31
    const int gchunk = (tid & 7) ^ (drow & 7);         // global chunk for slot tid&7
    const unsigned short* Kg = QK + (size_t)(b * 2048) * 2048 + 1024 + h * 64;
    const unsigned short* Vg = VT + (size_t)bh * 64 * 2048;
    // running global pointers (advance per 64-key tile)
    const unsigned short* kP0 = Kg + (size_t)(drow)      * 2048 + gchunk * 8;
    const unsigned short* kP1 = Kg + (size_t)(drow + 32) * 2048 + gchunk * 8;
    const unsigned short* vP0 = Vg + (size_t)(drow)      * 2048 + gchunk * 8;
    const unsigned short* vP1 = Vg + (size_t)(drow + 32) * 2048 + gchunk * 8;
    const int ldsOff = w * 512;                        // halfwords; +lane*8 by HW

    auto dma = [&](int buf, int t) {
        gload_lds16(kP0 + (size_t)t * 131072, &Ks [buf][ldsOff]);
        gload_lds16(kP1 + (size_t)t * 131072, &Ks [buf][2048 + ldsOff]);
        gload_lds16(vP0 + t * 64,             &Vts[buf][ldsOff]);
        gload_lds16(vP1 + t * 64,             &Vts[buf][2048 + ldsOff]);
    };

    dma(0, 0);

    const int qrow0 = b * 2048 + qb * 128 + w * 32;
    bf16x8 qf[2][2];   // B-frag of Q^T == A-frag of Q: Q[q=lr][dk=c*32+q4*8+j]
    #pragma unroll
    for (int u = 0; u < 2; ++u)
        #pragma unroll
        for (int c = 0; c < 2; ++c)
            qf[u][c] = *(const bf16x8*)&QK[(size_t)(qrow0 + u * 16 + lr) * 2048
                                           + h * 64 + c * 32 + q4 * 8];

    const int lr7 = lr & 7;

    // ones A-fragment (bf16 1.0) for denominator row-sum MFMA
    const short oneb = (short)0x3F80;
    const bf16x8 onesf = { oneb, oneb, oneb, oneb, oneb, oneb, oneb, oneb };

    f32x4 o[2][4] = {};      // O^T[d=jd*16+q4*4+p][q=u*16+lr]
    f32x4 lsum[2] = {};      // denominator: all rows equal = sum_k P^T[k][q=lr]
    int cur = 0;

    for (int t = 0; t < 32; ++t) {
        __syncthreads();                       // drains DMA(t) -> buf[cur] ready
        if (t + 1 < 32) dma(cur ^ 1, t + 1);   // in flight during compute

        #pragma unroll
        for (int kc = 0; kc < 2; ++kc) {
            // --- S^T for this 32-key chunk (2 mt subtiles) ---
            unsigned int pk[2][2][2];          // packed P^T words [u][ml][i]
            #pragma unroll
            for (int ml = 0; ml < 2; ++ml) {
                const int mt = kc * 2 + ml;
                f32x4 st[2] = {};
                __builtin_amdgcn_s_setprio(1);
                #pragma unroll
                for (int c = 0; c < 2; ++c) {
                    const int slot = (c * 4 + q4) ^ lr7;
                    bf16x8 kf = *(const bf16x8*)&Ks[cur][(mt * 16 + lr) * 64 + slot * 8];
                    #pragma unroll
                    for (int u = 0; u < 2; ++u)
                        st[u] = __builtin_amdgcn_mfma_f32_16x16x32_bf16(kf, qf[u][c], st[u], 0, 0, 0);
                }
                __builtin_amdgcn_s_setprio(0);
                #pragma unroll
                for (int u = 0; u < 2; ++u) {
                    float e0 = __builtin_amdgcn_exp2f(st[u][0]);
                    float e1 = __builtin_amdgcn_exp2f(st[u][1]);
                    float e2 = __builtin_amdgcn_exp2f(st[u][2]);
                    float e3 = __builtin_amdgcn_exp2f(st[u][3]);
                    pk[u][ml][0] = pack_bf2(e1, e0);
                    pk[u][ml][1] = pack_bf2(e3, e2);
                }
            }

            // --- lane exchange P^T -> PV B-frags (pure VALU permlane) ---
            bf16x8 pb[2];
            #pragma unroll
            for (int u = 0; u < 2; ++u) {
                uint2v a0 = __builtin_amdgcn_permlane32_swap(pk[u][0][0], pk[u][1][0], false, false);
                uint2v b0 = __builtin_amdgcn_permlane16_swap(a0[0], a0[1], false, false);
                uint2v a1 = __builtin_amdgcn_permlane32_swap(pk[u][0][1], pk[u][1][1], false, false);
                uint2v b1 = __builtin_amdgcn_permlane16_swap(a1[0], a1[1], false, false);
                int4 wv;
                wv.x = (int)b0[0];
                wv.y = (int)b1[0];
                wv.z = (int)b0[1];
                wv.w = (int)b1[1];
                pb[u] = *(bf16x8*)&wv;
            }

            // --- PV: O^T += V^T · P^T  (+ denominator row-sum) ---
            __builtin_amdgcn_s_setprio(1);
            #pragma unroll
            for (int u = 0; u < 2; ++u)
                lsum[u] = __builtin_amdgcn_mfma_f32_16x16x32_bf16(onesf, pb[u], lsum[u], 0, 0, 0);
            #pragma unroll
            for (int jd = 0; jd < 4; ++jd) {
                const int slot = (kc * 4 + q4) ^ lr7;
                bf16x8 vf = *(const bf16x8*)&Vts[cur][(jd * 16 + lr) * 64 + slot * 8];
                #pragma unroll
                for (int u = 0; u < 2; ++u)
                    o[u][jd] = __builtin_amdgcn_mfma_f32_16x16x32_bf16(vf, pb[u], o[u][jd], 0, 0, 0);
            }
            __builtin_amdgcn_s_setprio(0);
        }
        cur ^= 1;
    }

    #pragma unroll
    for (int u = 0; u < 2; ++u) {
        const float inv = __builtin_amdgcn_rcpf(lsum[u][0]);
        const size_t rowO = (size_t)(qrow0 + u * 16 + lr);
        #pragma unroll
        for (int jd = 0; jd < 4; ++jd) {
            ushortx4 v;
            #pragma unroll
            for (int p = 0; p < 4; ++p)
                v[p] = f2bf(o[u][jd][p] * inv);
            *(ushortx4*)&HC[rowO * 1024 + h * 64 + jd * 16 + q4 * 4] = v;
        }
    }
}

// ---------------------------------------------------------------------------
extern "C" void kernel_launch(void* const* d_in, const int* in_sizes, int n_in,
                              void* d_out, int out_size, void* d_ws, size_t ws_size,
                              hipStream_t stream)
{
    const float* x  = (const float*)d_in[0];
    const float* Wq = (const float*)d_in[1];
    const float* Wk = (const float*)d_in[2];
    const float* Wv = (const float*)d_in[3];
    const float* Wo = (const float*)d_in[4];
    float* out = (float*)d_out;

    char* ws = (char*)d_ws;
    unsigned short* XB    = (unsigned short*)(ws);              // 16777216 (aliases HC)
    unsigned short* HC    = (unsigned short*)(ws);
    unsigned short* WQKVT = (unsigned short*)(ws + 16777216);   // 6291456
    unsigned short* WOT   = (unsigned short*)(ws + 23068672);   // 2097152
    unsigned short* QK    = (unsigned short*)(ws + 25165824);   // 33554432
    unsigned short* VT    = (unsigned short*)(ws + 58720256);   // 16777216
    // total ws: 75497472 B (~72 MiB)

    pack_all<<<4608, 256, 0, stream>>>(x, Wq, Wk, Wv, Wo, XB, WQKVT, WOT);
    gemm_bt<1, 128><<<dim3(24, 64), 256, 0, stream>>>(XB, WQKVT, QK, VT, 8192, 3072, 1024, 0);
    attn_flash<<<dim3(64, 16), 256, 0, stream>>>(QK, VT, HC);
    gemm_bt<0, 128><<<dim3(8, 64), 256, 0, stream>>>(HC, WOT, out, nullptr, 8192, 1024, 1024, 1024);
}